// Round 11
// baseline (5031.839 us; speedup 1.0000x reference)
//
#include <hip/hip_runtime.h>

#define LRATE 1e-3f
static constexpr int Bn = 2048;
static constexpr int Dn = 784;
static constexpr int Hn = 256;
static constexpr int On = 10;
static constexpr int Cc = 64;           // chunk size
static constexpr int NCHUNK = Bn / Cc;  // 32

// LDS row strides (floats): multiples of 4 for aligned float4 (ds_read_b128)
static constexpr int AS = 68;   // 64x64 matrices
static constexpr int YS = 260;  // 64x256 matrices
static constexpr int MSZ = 64 * AS;  // 4352 floats per 64x64 matrix

// 4-lane-group sum via DPP quad_perm (pure VALU; no ds_bpermute)
__device__ __forceinline__ float red4(float s) {
  s += __uint_as_float(__builtin_amdgcn_mov_dpp(__float_as_uint(s), 0xB1, 0xF, 0xF, true)); // xor 1
  s += __uint_as_float(__builtin_amdgcn_mov_dpp(__float_as_uint(s), 0x4E, 0xF, 0xF, true)); // xor 2
  return s;
}

// ---------------------------------------------------------------------------
// Kernel 0: reset the heater flag (graph-safe; runs once per kernel_launch)
// ---------------------------------------------------------------------------
__global__ void init_flag_kernel(int* flag) { *flag = 0; }

// ---------------------------------------------------------------------------
// Kernel 1: whitening  xw[b,d] = sum_e (x[b,e]-mean[e]) * M[d,e]
// ---------------------------------------------------------------------------
__global__ __launch_bounds__(256) void whiten_kernel(
    const float* __restrict__ x, const float* __restrict__ mean,
    const float* __restrict__ Mw, float* __restrict__ xw)
{
  __shared__ __align__(16) float As[16][64];
  __shared__ __align__(16) float Bs[16][64];
  const int tid = threadIdx.x;
  const int b0 = blockIdx.x * 64;
  const int d0 = blockIdx.y * 64;
  const int mrow = tid >> 2;
  const int kq = (tid & 3) << 2;
  const int ty = tid >> 4, tx = tid & 15;

  float acc[4][4];
#pragma unroll
  for (int i = 0; i < 4; ++i)
#pragma unroll
    for (int j = 0; j < 4; ++j) acc[i][j] = 0.f;

  for (int k0 = 0; k0 < Dn; k0 += 16) {
    __syncthreads();
    {
      const float4 av = *(const float4*)&x[(b0 + mrow) * Dn + k0 + kq];
      const float4 mv = *(const float4*)&mean[k0 + kq];
      As[kq + 0][mrow] = av.x - mv.x;
      As[kq + 1][mrow] = av.y - mv.y;
      As[kq + 2][mrow] = av.z - mv.z;
      As[kq + 3][mrow] = av.w - mv.w;
      float4 bv = make_float4(0.f, 0.f, 0.f, 0.f);
      if (d0 + mrow < Dn) bv = *(const float4*)&Mw[(d0 + mrow) * Dn + k0 + kq];
      Bs[kq + 0][mrow] = bv.x;
      Bs[kq + 1][mrow] = bv.y;
      Bs[kq + 2][mrow] = bv.z;
      Bs[kq + 3][mrow] = bv.w;
    }
    __syncthreads();
#pragma unroll
    for (int k = 0; k < 16; ++k) {
      const float4 a = *(const float4*)&As[k][ty << 2];
      const float4 b = *(const float4*)&Bs[k][tx << 2];
      acc[0][0] += a.x * b.x; acc[0][1] += a.x * b.y; acc[0][2] += a.x * b.z; acc[0][3] += a.x * b.w;
      acc[1][0] += a.y * b.x; acc[1][1] += a.y * b.y; acc[1][2] += a.y * b.z; acc[1][3] += a.y * b.w;
      acc[2][0] += a.z * b.x; acc[2][1] += a.z * b.y; acc[2][2] += a.z * b.z; acc[2][3] += a.z * b.w;
      acc[3][0] += a.w * b.x; acc[3][1] += a.w * b.y; acc[3][2] += a.w * b.z; acc[3][3] += a.w * b.w;
    }
  }
  const int col = d0 + (tx << 2);
  if (col < Dn) {
#pragma unroll
    for (int i = 0; i < 4; ++i) {
      const int row = b0 + (ty << 2) + i;
      *(float4*)&xw[row * Dn + col] =
          make_float4(acc[i][0], acc[i][1], acc[i][2], acc[i][3]);
    }
  }
}

// ---------------------------------------------------------------------------
// Kernel 2: per-chunk Gram blocks  S_c = X_c X_c^T   (all chunks, parallel)
// NOTE: acc[a][b] summation order is identical for (i,j) and (j,i) =>
// S is BIT-EXACTLY symmetric (seq_kernel relies on this for row reads).
// ---------------------------------------------------------------------------
__global__ __launch_bounds__(256) void sgram_kernel(
    const float* __restrict__ xw, float* __restrict__ S_all)
{
  __shared__ __align__(16) float Xs[64 * 396];  // 64 x 392 staged (stride 396)
  const int t = threadIdx.x;
  const int c = blockIdx.x;
  const float* xc = xw + (size_t)c * Cc * Dn;
  const int ti = t >> 4, tj = t & 15;
  float acc[4][4];
#pragma unroll
  for (int a = 0; a < 4; ++a)
#pragma unroll
    for (int b = 0; b < 4; ++b) acc[a][b] = 0.f;

  for (int pass = 0; pass < 2; ++pass) {
    __syncthreads();
    for (int e4 = t; e4 < 64 * 98; e4 += 256) {
      const int r = e4 / 98, c4 = e4 - r * 98;
      *(float4*)&Xs[r * 396 + 4 * c4] =
          *(const float4*)&xc[r * Dn + pass * 392 + 4 * c4];
    }
    __syncthreads();
    for (int k4 = 0; k4 < 98; ++k4) {
      float4 A[4], Bv[4];
#pragma unroll
      for (int a = 0; a < 4; ++a) A[a] = *(const float4*)&Xs[(4 * ti + a) * 396 + 4 * k4];
#pragma unroll
      for (int b = 0; b < 4; ++b) Bv[b] = *(const float4*)&Xs[(4 * tj + b) * 396 + 4 * k4];
#pragma unroll
      for (int a = 0; a < 4; ++a)
#pragma unroll
        for (int b = 0; b < 4; ++b)
          acc[a][b] += A[a].x * Bv[b].x + A[a].y * Bv[b].y + A[a].z * Bv[b].z + A[a].w * Bv[b].w;
    }
  }
  float* Sc = S_all + (size_t)c * Cc * Cc;
#pragma unroll
  for (int a = 0; a < 4; ++a)
#pragma unroll
    for (int b = 0; b < 4; ++b)
      Sc[(4 * ti + a) * Cc + 4 * tj + b] = acc[a][b];
}

// ---------------------------------------------------------------------------
// Kernel 3 (per chunk): yhat[r][h] = sum_d X_c[r][d] * W[h][d]   [64 x 256]
// ---------------------------------------------------------------------------
__global__ __launch_bounds__(256) void yhat_kernel(
    const float* __restrict__ xc, const float* __restrict__ W,
    float* __restrict__ yhat)
{
  const int t = threadIdx.x;
  const int r = t & 63, hh = t >> 6;
  const int h = blockIdx.x * 4 + hh;
  const float4* xr = (const float4*)&xc[r * Dn];
  const float4* wr = (const float4*)&W[h * Dn];
  float acc = 0.f;
#pragma unroll 4
  for (int f = 0; f < 196; ++f) {
    const float4 a = xr[f], b = wr[f];
    acc += a.x * b.x + a.y * b.y + a.z * b.z + a.w * b.w;
  }
  yhat[r * Hn + h] = acc;
}

// ---------------------------------------------------------------------------
// Kernel 4 (per chunk): 64-step recurrence, BLOCKED by R=4.
// Worker (block 0) is BIT-IDENTICAL to the round-10-passing version.
// Blocks 1..255 are HEATERS: one per CU (146KB LDS => 1 block/CU); they spin
// on a device-scope flag burning bounded FMAs so the DVFS governor keeps
// clocks boosted during the otherwise 1-CU sequential phase. They write
// nothing; spin count varies per run but output does not (deterministic).
// ---------------------------------------------------------------------------
__global__ __launch_bounds__(256, 1) void seq_kernel(
    const float* __restrict__ yhat_g, const float* __restrict__ S_g,
    float* __restrict__ feats_c, float* __restrict__ beta_g,
    int* __restrict__ flag, int target)
{
  if (blockIdx.x != 0) {
    // ---- heater: burn VALU until worker bumps the flag ----
    float a = 1.0f + (float)(threadIdx.x & 7);
    float b = 0.5f + (float)(blockIdx.x & 3);
    float c = 0.25f, d = 1.5f;
    while (__hip_atomic_load(flag, __ATOMIC_RELAXED, __HIP_MEMORY_SCOPE_AGENT) < target) {
#pragma unroll 64
      for (int i = 0; i < 256; ++i) {
        a = fmaf(a, 0.999999f, 1.000001f);
        b = fmaf(b, 0.999998f, 0.999999f);
        c = fmaf(c, 0.999997f, 1.000002f);
        d = fmaf(d, 0.999996f, 1.000003f);
      }
      asm volatile("" :: "v"(a), "v"(b), "v"(c), "v"(d));
    }
    return;
  }

  __shared__ __align__(16) float lds[8 * MSZ + 1872];  // 146,752 B
  float* Gy  = lds + 0 * MSZ;
  float* AlT = lds + 1 * MSZ;
  float* BeT = lds + 2 * MSZ;
  float* GuT = lds + 3 * MSZ;
  float* Qs  = lds + 4 * MSZ;
  float* Ts  = lds + 5 * MSZ;
  float* Ss  = lds + 6 * MSZ;
  float* Al  = lds + 7 * MSZ;
  float* VOb = lds + 8 * MSZ;        // [4][AS] (row-major by s, for ph1b dots)
  float* VMb = VOb + 4 * AS;         // [4][AS], zeroed at block positions
  float* GVo = VMb + 4 * AS;         // [16]:  GVo[s'*4 + s]
  float* Pk  = GVo + 16;             // [64][20]: og[4]|oq[4]|oa[4]|vo[4]|pad
  // epilogue stages yh (16640 floats) over Gy..GuT (17408); Ts/Ss/Al intact.

  const int t = threadIdx.x;
  const int k = t >> 2, qr = t & 3;
  const int m0q = qr * 16;

  // ---- prologue: zero Gy,AlT,BeT,GuT,Qs (contiguous 5*MSZ) ----
  for (int e4 = t; e4 < 5 * MSZ / 4; e4 += 256)
    *(float4*)&lds[4 * e4] = make_float4(0.f, 0.f, 0.f, 0.f);
  // Ss <- S_g (rows stride AS)
  for (int e4 = t; e4 < 1024; e4 += 256) {
    const int r = e4 >> 4, c4 = e4 & 15;
    *(float4*)&Ss[r * AS + 4 * c4] = ((const float4*)S_g)[e4];
  }
  // Ts = yhat yhat^T from global (16x16 grid, 4x4 blocks) — bit-symmetric
  {
    const int ti = t >> 4, tj = t & 15;
    float acc[4][4];
#pragma unroll
    for (int a = 0; a < 4; ++a)
#pragma unroll
      for (int b = 0; b < 4; ++b) acc[a][b] = 0.f;
    for (int k4 = 0; k4 < 64; ++k4) {
      float4 A[4], Bv[4];
#pragma unroll
      for (int a = 0; a < 4; ++a) A[a] = *(const float4*)&yhat_g[(4 * ti + a) * Hn + 4 * k4];
#pragma unroll
      for (int b = 0; b < 4; ++b) Bv[b] = *(const float4*)&yhat_g[(4 * tj + b) * Hn + 4 * k4];
#pragma unroll
      for (int a = 0; a < 4; ++a)
#pragma unroll
        for (int b = 0; b < 4; ++b)
          acc[a][b] += A[a].x * Bv[b].x + A[a].y * Bv[b].y + A[a].z * Bv[b].z + A[a].w * Bv[b].w;
    }
#pragma unroll
    for (int a = 0; a < 4; ++a)
#pragma unroll
      for (int b = 0; b < 4; ++b)
        Ts[(4 * ti + a) * AS + 4 * tj + b] = acc[a][b];
  }
  __syncthreads();

  const float4* gyseg = (const float4*)&Gy[k * AS + m0q];
  const float4* atseg = (const float4*)&AlT[k * AS + m0q];
  const float4* qseg  = (const float4*)&Qs[k * AS + m0q];
  const float4* beseg = (const float4*)&BeT[k * AS + m0q];
  const float4* guseg = (const float4*)&GuT[k * AS + m0q];

  for (int b = 0; b < Cc / 4; ++b) {
    const int b0 = 4 * b;
    // ================= ph1a: outer dots =================
    float4 gyS[4], atS[4], qS[4];
#pragma unroll
    for (int f = 0; f < 4; ++f) { gyS[f] = gyseg[f]; atS[f] = atseg[f]; qS[f] = qseg[f]; }
    float og[4], oq[4], oa[4], grow[4];
#pragma unroll
    for (int s = 0; s < 4; ++s) {
      const float4* pR = (const float4*)&GuT[(b0 + s) * AS + m0q];
      float g0 = 0.f, g1 = 0.f, g2 = 0.f, g3 = 0.f;
      float a0 = 0.f, a1 = 0.f, a2 = 0.f, a3 = 0.f;
      float w0 = 0.f, w1 = 0.f, w2 = 0.f, w3 = 0.f;
#pragma unroll
      for (int f = 0; f < 4; ++f) {
        const float4 p = pR[f];
        g0 += p.x * gyS[f].x; g1 += p.y * gyS[f].y; g2 += p.z * gyS[f].z; g3 += p.w * gyS[f].w;
        a0 += p.x * atS[f].x; a1 += p.y * atS[f].y; a2 += p.z * atS[f].z; a3 += p.w * atS[f].w;
        w0 += p.x * qS[f].x;  w1 += p.y * qS[f].y;  w2 += p.z * qS[f].z;  w3 += p.w * qS[f].w;
      }
      og[s] = red4((g0 + g1) + (g2 + g3));
      oa[s] = red4((a0 + a1) + (a2 + a3));
      oq[s] = red4((w0 + w1) + (w2 + w3));
      grow[s] = Gy[(b0 + s) * AS + k];
    }
    if (qr == 0)      *(float4*)&Pk[k * 20 + 0] = make_float4(og[0], og[1], og[2], og[3]);
    else if (qr == 1) *(float4*)&Pk[k * 20 + 4] = make_float4(oq[0], oq[1], oq[2], oq[3]);
    else if (qr == 2) *(float4*)&Pk[k * 20 + 8] = make_float4(oa[0], oa[1], oa[2], oa[3]);
    else {
      float vo[4];
#pragma unroll
      for (int s = 0; s < 4; ++s) vo[s] = grow[s] + LRATE * oq[s];
      *(float4*)&Pk[k * 20 + 12] = make_float4(vo[0], vo[1], vo[2], vo[3]);
#pragma unroll
      for (int s = 0; s < 4; ++s) VOb[s * AS + k] = vo[s];
    }
    __syncthreads();

    // ================= ph1b: GVo pair dots =================
    if (t < 64) {
      const int pr = t >> 2;          // 0..15: s' = pr>>2, s = pr&3
      const int sp = pr >> 2, s2 = pr & 3;
      const int q2 = t & 3;
      const float4* gr = (const float4*)&GuT[(b0 + sp) * AS + q2 * 16];
      const float4* vr = (const float4*)&VOb[s2 * AS + q2 * 16];
      float d0 = 0.f, d1 = 0.f, d2 = 0.f, d3 = 0.f;
#pragma unroll
      for (int f = 0; f < 4; ++f) {
        const float4 g = gr[f], v = vr[f];
        d0 += g.x * v.x; d1 += g.y * v.y; d2 += g.z * v.z; d3 += g.w * v.w;
      }
      const float d = red4((d0 + d1) + (d2 + d3));
      if (q2 == 0) GVo[pr] = d;
    }
    __syncthreads();

    // ================= ph2: redundant 4x4 inner solve =================
    float T8[4][4], S8v[4][4], OG8[4][4], OQ8[4][4], GV8[4][4];
#pragma unroll
    for (int j = 0; j < 4; ++j) {
      const float4 t4 = *(const float4*)&Ts[(b0 + j) * AS + b0];  // T row (sym)
      T8[j][0] = t4.x; T8[j][1] = t4.y; T8[j][2] = t4.z; T8[j][3] = t4.w;
      const float4 s4 = *(const float4*)&Ss[(b0 + j) * AS + b0];  // S row (sym)
      S8v[j][0] = s4.x; S8v[j][1] = s4.y; S8v[j][2] = s4.z; S8v[j][3] = s4.w;
      const float4 g4 = *(const float4*)&Pk[(b0 + j) * 20 + 0];   // og col j
      OG8[0][j] = g4.x; OG8[1][j] = g4.y; OG8[2][j] = g4.z; OG8[3][j] = g4.w;
      const float4 q4 = *(const float4*)&Pk[(b0 + j) * 20 + 4];   // oq col j
      OQ8[0][j] = q4.x; OQ8[1][j] = q4.y; OQ8[2][j] = q4.z; OQ8[3][j] = q4.w;
      const float4 v4 = ((const float4*)GVo)[j];
      GV8[j][0] = v4.x; GV8[j][1] = v4.y; GV8[j][2] = v4.z; GV8[j][3] = v4.w;
    }
    float G8[4][4], V8[4][4], U8[4][4], W8[4][4], Qd[4];
    // s = 0
#pragma unroll
    for (int j = 0; j < 4; ++j) {
      G8[0][j] = T8[0][j] + LRATE * OG8[0][j];
      V8[0][j] = 0.f;
      W8[j][0] = GV8[j][0];
    }
#pragma unroll
    for (int j = 0; j < 4; ++j) U8[0][j] = S8v[0][j] - G8[0][j] - LRATE * W8[j][0];
    Qd[0] = G8[0][0] + LRATE * W8[0][0];
    // s = 1
    {
      const float p0 = U8[0][1];
#pragma unroll
      for (int j = 0; j < 4; ++j) G8[1][j] = T8[1][j] + LRATE * (OG8[1][j] + p0 * G8[0][j]);
      V8[1][0] = G8[0][1] + LRATE * (OQ8[1][0] + p0 * Qd[0]);
      V8[1][1] = V8[1][2] = V8[1][3] = 0.f;
#pragma unroll
      for (int j = 0; j < 4; ++j) W8[j][1] = GV8[j][1] + LRATE * (p0 * W8[j][0]);
#pragma unroll
      for (int j = 0; j < 4; ++j)
        U8[1][j] = S8v[1][j] - G8[1][j] - LRATE * (W8[j][1] + V8[1][0] * U8[0][j]);
      Qd[1] = G8[1][1] + LRATE * (W8[1][1] + p0 * V8[1][0]);
    }
    // s = 2
    {
      const float p0 = U8[0][2], p1 = U8[1][2];
#pragma unroll
      for (int j = 0; j < 4; ++j)
        G8[2][j] = T8[2][j] + LRATE * (OG8[2][j] + p0 * G8[0][j] + p1 * G8[1][j]);
      V8[2][0] = G8[0][2] + LRATE * (OQ8[2][0] + p0 * Qd[0] + p1 * V8[1][0]);
      V8[2][1] = G8[1][2] + LRATE * (OQ8[2][1] + p1 * Qd[1]);  // p0*V8[0][1] = 0
      V8[2][2] = V8[2][3] = 0.f;
#pragma unroll
      for (int j = 0; j < 4; ++j) W8[j][2] = GV8[j][2] + LRATE * (p0 * W8[j][0] + p1 * W8[j][1]);
#pragma unroll
      for (int j = 0; j < 4; ++j)
        U8[2][j] = S8v[2][j] - G8[2][j] -
                   LRATE * (W8[j][2] + V8[2][0] * U8[0][j] + V8[2][1] * U8[1][j]);
      Qd[2] = G8[2][2] + LRATE * (W8[2][2] + p0 * V8[2][0] + p1 * V8[2][1]);
    }
    // s = 3
    {
      const float p0 = U8[0][3], p1 = U8[1][3], p2 = U8[2][3];
#pragma unroll
      for (int j = 0; j < 4; ++j)
        G8[3][j] = T8[3][j] + LRATE * (OG8[3][j] + p0 * G8[0][j] + p1 * G8[1][j] + p2 * G8[2][j]);
      V8[3][0] = G8[0][3] + LRATE * (OQ8[3][0] + p0 * Qd[0] + p1 * V8[1][0] + p2 * V8[2][0]);
      V8[3][1] = G8[1][3] + LRATE * (OQ8[3][1] + p1 * Qd[1] + p2 * V8[2][1]);
      V8[3][2] = G8[2][3] + LRATE * (OQ8[3][2] + p2 * Qd[2]);
      V8[3][3] = 0.f;
#pragma unroll
      for (int j = 0; j < 4; ++j)
        W8[j][3] = GV8[j][3] + LRATE * (p0 * W8[j][0] + p1 * W8[j][1] + p2 * W8[j][2]);
#pragma unroll
      for (int j = 0; j < 4; ++j)
        U8[3][j] = S8v[3][j] - G8[3][j] -
                   LRATE * (W8[j][3] + V8[3][0] * U8[0][j] + V8[3][1] * U8[1][j] +
                            V8[3][2] * U8[2][j]);
      Qd[3] = G8[3][3] + LRATE * (W8[3][3] + p0 * V8[3][0] + p1 * V8[3][1] + p2 * V8[3][2]);
    }

    // ================= ph3: per-thread triangular expansion =================
    float TsK[4], OGk[4], OAk[4], VOk[4];
    {
      const float4 tk4 = *(const float4*)&Ts[k * AS + b0];    // Ts sym row read
      TsK[0] = tk4.x; TsK[1] = tk4.y; TsK[2] = tk4.z; TsK[3] = tk4.w;
      const float4 og4 = *(const float4*)&Pk[k * 20 + 0];
      OGk[0] = og4.x; OGk[1] = og4.y; OGk[2] = og4.z; OGk[3] = og4.w;
      const float4 oa4 = *(const float4*)&Pk[k * 20 + 8];
      OAk[0] = oa4.x; OAk[1] = oa4.y; OAk[2] = oa4.z; OAk[3] = oa4.w;
      const float4 vo4 = *(const float4*)&Pk[k * 20 + 12];
      VOk[0] = vo4.x; VOk[1] = vo4.y; VOk[2] = vo4.z; VOk[3] = vo4.w;
    }
    float gy[4], aI[4], vm[4];
    // s=0
    gy[0] = TsK[0] + LRATE * OGk[0];
    { const float a = LRATE * OAk[0]; aI[0] = (k < b0) ? a : ((k == b0) ? 1.f : 0.f); }
    vm[0] = (k < b0) ? VOk[0] : 0.f;
    // s=1
    {
      const float p0 = U8[0][1];
      gy[1] = TsK[1] + LRATE * (OGk[1] + p0 * gy[0]);
      const float a = LRATE * (OAk[1] + p0 * aI[0]);
      aI[1] = (k < b0 + 1) ? a : ((k == b0 + 1) ? 1.f : 0.f);
      const float vt0 = (k == b0) ? Qd[0] : vm[0];
      float v = VOk[1] + LRATE * (p0 * vt0);
      if (k == b0) v += G8[0][1];
      vm[1] = (k < b0 + 1) ? v : 0.f;
    }
    // s=2
    {
      const float p0 = U8[0][2], p1 = U8[1][2];
      gy[2] = TsK[2] + LRATE * (OGk[2] + p0 * gy[0] + p1 * gy[1]);
      const float a = LRATE * (OAk[2] + p0 * aI[0] + p1 * aI[1]);
      aI[2] = (k < b0 + 2) ? a : ((k == b0 + 2) ? 1.f : 0.f);
      const float vt0 = (k == b0) ? Qd[0] : vm[0];
      const float vt1 = (k == b0 + 1) ? Qd[1] : vm[1];
      float v = VOk[2] + LRATE * (p0 * vt0 + p1 * vt1);
      if (k == b0) v += G8[0][2];
      else if (k == b0 + 1) v += G8[1][2];
      vm[2] = (k < b0 + 2) ? v : 0.f;
    }
    // s=3
    {
      const float p0 = U8[0][3], p1 = U8[1][3], p2 = U8[2][3];
      gy[3] = TsK[3] + LRATE * (OGk[3] + p0 * gy[0] + p1 * gy[1] + p2 * gy[2]);
      const float a = LRATE * (OAk[3] + p0 * aI[0] + p1 * aI[1] + p2 * aI[2]);
      aI[3] = (k < b0 + 3) ? a : ((k == b0 + 3) ? 1.f : 0.f);
      const float vt0 = (k == b0) ? Qd[0] : vm[0];
      const float vt1 = (k == b0 + 1) ? Qd[1] : vm[1];
      const float vt2 = (k == b0 + 2) ? Qd[2] : vm[2];
      float v = VOk[3] + LRATE * (p0 * vt0 + p1 * vt1 + p2 * vt2);
      if (k == b0) v += G8[0][3];
      else if (k == b0 + 1) v += G8[1][3];
      else if (k == b0 + 2) v += G8[2][3];
      vm[3] = (k < b0 + 3) ? v : 0.f;
    }
    // Q writes carry Qd at the diagonal from every writer (race-safe: all
    // writers store the same value). qw[s] = (k==b0+s) ? Qd[s] : vm[s].
    float qw[4];
#pragma unroll
    for (int s = 0; s < 4; ++s) qw[s] = (k == b0 + s) ? Qd[s] : vm[s];
    if (qr == 0) {
      *(float4*)&Gy[k * AS + b0] = make_float4(gy[0], gy[1], gy[2], gy[3]);
#pragma unroll
      for (int s = 0; s < 4; ++s) Qs[(b0 + s) * AS + k] = qw[s];
    } else if (qr == 1) {
      *(float4*)&AlT[k * AS + b0] = make_float4(aI[0], aI[1], aI[2], aI[3]);
      *(float4*)&Qs[k * AS + b0] = make_float4(qw[0], qw[1], qw[2], qw[3]);
    } else if (qr == 2) {
#pragma unroll
      for (int s = 0; s < 4; ++s) Al[(b0 + s) * AS + k] = aI[s];
#pragma unroll
      for (int s = 0; s < 4; ++s) VMb[s * AS + k] = (k < b0) ? vm[s] : 0.f;
    }
    __syncthreads();

    // ================= ph4: b / gu =================
    float4 beS[4], guS[4];
#pragma unroll
    for (int f = 0; f < 4; ++f) { beS[f] = beseg[f]; guS[f] = guseg[f]; }
    float bO[4], gO[4];
#pragma unroll
    for (int s = 0; s < 4; ++s) {
      const float4* vmr = (const float4*)&VMb[s * AS + m0q];
      float b0a = 0.f, b1a = 0.f, b2a = 0.f, b3a = 0.f;
      float u0 = 0.f, u1 = 0.f, u2 = 0.f, u3 = 0.f;
#pragma unroll
      for (int f = 0; f < 4; ++f) {
        const float4 v = vmr[f];
        b0a += v.x * beS[f].x; b1a += v.y * beS[f].y; b2a += v.z * beS[f].z; b3a += v.w * beS[f].w;
        u0 += v.x * guS[f].x; u1 += v.y * guS[f].y; u2 += v.z * guS[f].z; u3 += v.w * guS[f].w;
      }
      bO[s] = red4((b0a + b1a) + (b2a + b3a));
      gO[s] = red4((u0 + u1) + (u2 + u3));
    }
    float SsK[4];
    {
      const float4 sk4 = *(const float4*)&Ss[k * AS + b0];    // Ss sym row read
      SsK[0] = sk4.x; SsK[1] = sk4.y; SsK[2] = sk4.z; SsK[3] = sk4.w;
    }
    float bI[4], gu[4];
    {
      const float bb = -LRATE * bO[0];
      bI[0] = (k < b0) ? bb : ((k == b0) ? 1.f : 0.f);
      gu[0] = SsK[0] - gy[0] - LRATE * gO[0];
    }
    {
      const float bb = -LRATE * (bO[1] + V8[1][0] * bI[0]);
      bI[1] = (k < b0 + 1) ? bb : ((k == b0 + 1) ? 1.f : 0.f);
      gu[1] = SsK[1] - gy[1] - LRATE * (gO[1] + V8[1][0] * gu[0]);
    }
    {
      const float bb = -LRATE * (bO[2] + V8[2][0] * bI[0] + V8[2][1] * bI[1]);
      bI[2] = (k < b0 + 2) ? bb : ((k == b0 + 2) ? 1.f : 0.f);
      gu[2] = SsK[2] - gy[2] - LRATE * (gO[2] + V8[2][0] * gu[0] + V8[2][1] * gu[1]);
    }
    {
      const float bb = -LRATE * (bO[3] + V8[3][0] * bI[0] + V8[3][1] * bI[1] + V8[3][2] * bI[2]);
      bI[3] = (k < b0 + 3) ? bb : ((k == b0 + 3) ? 1.f : 0.f);
      gu[3] = SsK[3] - gy[3] -
              LRATE * (gO[3] + V8[3][0] * gu[0] + V8[3][1] * gu[1] + V8[3][2] * gu[2]);
    }
    if (qr == 0) {
      *(float4*)&GuT[k * AS + b0] = make_float4(gu[0], gu[1], gu[2], gu[3]);
    } else if (qr == 1) {
      *(float4*)&BeT[k * AS + b0] = make_float4(bI[0], bI[1], bI[2], bI[3]);
    }
    __syncthreads();
  }

  // ---- epilogue 1: beta export (transpose from BeT; row-major beta_g) ----
  {
    const int r = t >> 2, q = t & 3;
#pragma unroll
    for (int kk = 0; kk < 16; ++kk) {
      const int kcol = q * 16 + kk;
      beta_g[r * 64 + kcol] = BeT[kcol * AS + r];
    }
  }
  __syncthreads();

  // ---- epilogue 2: stage yh over Gy..GuT (stride YS); Ts/Ss/Al untouched ----
  for (int e4 = t; e4 < 4096; e4 += 256) {
    const int r = e4 >> 6, c4 = e4 & 63;
    *(float4*)&lds[r * YS + 4 * c4] = ((const float4*)yhat_g)[e4];
  }
  __syncthreads();

  // ---- epilogue 3: feats = alpha * yh (alpha rows from Al) ----
  {
    const int r = k;  // t>>2
    const int m0q4 = m0q * 4;
    float a[64];
#pragma unroll
    for (int f = 0; f < 16; ++f) {
      const float4 av = *(const float4*)&Al[r * AS + 4 * f];
      a[4 * f + 0] = av.x; a[4 * f + 1] = av.y;
      a[4 * f + 2] = av.z; a[4 * f + 3] = av.w;
    }
    float4 acc[16];
#pragma unroll
    for (int f = 0; f < 16; ++f) acc[f] = make_float4(0.f, 0.f, 0.f, 0.f);
#pragma unroll
    for (int m4 = 0; m4 < 16; ++m4) {
      const float av0 = a[4 * m4 + 0], av1 = a[4 * m4 + 1];
      const float av2 = a[4 * m4 + 2], av3 = a[4 * m4 + 3];
      const float4* y0 = (const float4*)&lds[(4 * m4 + 0) * YS + m0q4];
      const float4* y1 = (const float4*)&lds[(4 * m4 + 1) * YS + m0q4];
      const float4* y2 = (const float4*)&lds[(4 * m4 + 2) * YS + m0q4];
      const float4* y3 = (const float4*)&lds[(4 * m4 + 3) * YS + m0q4];
#pragma unroll
      for (int f = 0; f < 16; ++f) {
        const float4 z0 = y0[f], z1 = y1[f], z2 = y2[f], z3 = y3[f];
        acc[f].x += av0 * z0.x + av1 * z1.x + av2 * z2.x + av3 * z3.x;
        acc[f].y += av0 * z0.y + av1 * z1.y + av2 * z2.y + av3 * z3.y;
        acc[f].z += av0 * z0.z + av1 * z1.z + av2 * z2.z + av3 * z3.z;
        acc[f].w += av0 * z0.w + av1 * z1.w + av2 * z2.w + av3 * z3.w;
      }
    }
    float4* dst = (float4*)&feats_c[r * Hn + m0q4];
#pragma unroll
    for (int f = 0; f < 16; ++f) dst[f] = acc[f];
  }
  __syncthreads();
  // release heaters
  if (t == 0) {
    __threadfence();
    atomicAdd(flag, 1);
  }
}

// ---------------------------------------------------------------------------
// Kernel 5 (per chunk): V = X_c - Y W ; U = beta V ; W += LR * Y^T U.
// grid 98 WGs, each owns 8 consecutive W columns.
// ---------------------------------------------------------------------------
__global__ __launch_bounds__(256, 1) void upd_kernel(
    const float* __restrict__ xc, const float* __restrict__ Yg,
    const float* __restrict__ beta_g, float* __restrict__ W)
{
  __shared__ __align__(16) float Yl[64 * YS];
  __shared__ __align__(16) float bl[64 * AS];
  __shared__ __align__(16) float WlT[8 * YS];
  __shared__ __align__(16) float XT[8 * 64];
  __shared__ __align__(16) float VT[8 * 64];
  __shared__ __align__(16) float UT[8 * 64];
  const int t = threadIdx.x;
  const int d0 = blockIdx.x * 8;

  {  // load Y
    const int r = t >> 2, qr = t & 3;
    const float4* src = (const float4*)&Yg[r * Hn + qr * 64];
    float4* dst = (float4*)&Yl[r * YS + qr * 64];
#pragma unroll
    for (int f = 0; f < 16; ++f) dst[f] = src[f];
  }
#pragma unroll
  for (int f = 0; f < 4; ++f) {  // load beta
    const int e4 = t + 256 * f;
    const int r = e4 >> 4, c4 = e4 & 15;
    *(float4*)&bl[r * AS + 4 * c4] = ((const float4*)beta_g)[e4];
  }
  {  // load W slice (transposed)
    const float4* wsrc = (const float4*)&W[t * Dn + d0];
    const float4 w0 = wsrc[0], w1 = wsrc[1];
    WlT[0 * YS + t] = w0.x; WlT[1 * YS + t] = w0.y; WlT[2 * YS + t] = w0.z; WlT[3 * YS + t] = w0.w;
    WlT[4 * YS + t] = w1.x; WlT[5 * YS + t] = w1.y; WlT[6 * YS + t] = w1.z; WlT[7 * YS + t] = w1.w;
  }
  if (t < 64) {  // load X slice (transposed)
    const float4* xsrc = (const float4*)&xc[t * Dn + d0];
    const float4 x0 = xsrc[0], x1 = xsrc[1];
    XT[0 * 64 + t] = x0.x; XT[1 * 64 + t] = x0.y; XT[2 * 64 + t] = x0.z; XT[3 * 64 + t] = x0.w;
    XT[4 * 64 + t] = x1.x; XT[5 * 64 + t] = x1.y; XT[6 * 64 + t] = x1.z; XT[7 * 64 + t] = x1.w;
  }
  __syncthreads();
  const int r = t & 63, da = t >> 6, db = da + 4;
  {  // V = X - Y W
    float va = XT[da * 64 + r], vb = XT[db * 64 + r];
    const float4* yrow = (const float4*)&Yl[r * YS];
    const float4* wa = (const float4*)&WlT[da * YS];
    const float4* wb = (const float4*)&WlT[db * YS];
#pragma unroll 8
    for (int f = 0; f < 64; ++f) {
      const float4 y = yrow[f], A = wa[f], Bv = wb[f];
      va -= y.x * A.x + y.y * A.y + y.z * A.z + y.w * A.w;
      vb -= y.x * Bv.x + y.y * Bv.y + y.z * Bv.z + y.w * Bv.w;
    }
    VT[da * 64 + r] = va; VT[db * 64 + r] = vb;
  }
  __syncthreads();
  {  // U = beta V
    float ua = 0.f, ub = 0.f;
    const float4* br = (const float4*)&bl[r * AS];
    const float4* vta = (const float4*)&VT[da * 64];
    const float4* vtb = (const float4*)&VT[db * 64];
#pragma unroll
    for (int f = 0; f < 16; ++f) {
      const float4 b = br[f], A = vta[f], Bv = vtb[f];
      ua += b.x * A.x + b.y * A.y + b.z * A.z + b.w * A.w;
      ub += b.x * Bv.x + b.y * Bv.y + b.z * Bv.z + b.w * Bv.w;
    }
    UT[da * 64 + r] = ua; UT[db * 64 + r] = ub;
  }
  __syncthreads();
  {  // W[h=t][d0+dj] += LR * sum_r Y[r][h] * U[r][dj]
    float wacc[8];
#pragma unroll
    for (int dj = 0; dj < 8; ++dj) wacc[dj] = 0.f;
    for (int r4 = 0; r4 < 16; ++r4) {
      float4 u[8];
#pragma unroll
      for (int dj = 0; dj < 8; ++dj) u[dj] = *(const float4*)&UT[dj * 64 + 4 * r4];
      const float y0 = Yl[(4 * r4 + 0) * YS + t];
      const float y1 = Yl[(4 * r4 + 1) * YS + t];
      const float y2 = Yl[(4 * r4 + 2) * YS + t];
      const float y3 = Yl[(4 * r4 + 3) * YS + t];
#pragma unroll
      for (int dj = 0; dj < 8; ++dj)
        wacc[dj] += y0 * u[dj].x + y1 * u[dj].y + y2 * u[dj].z + y3 * u[dj].w;
    }
    float4 o0, o1;
    o0.x = WlT[0 * YS + t] + LRATE * wacc[0];
    o0.y = WlT[1 * YS + t] + LRATE * wacc[1];
    o0.z = WlT[2 * YS + t] + LRATE * wacc[2];
    o0.w = WlT[3 * YS + t] + LRATE * wacc[3];
    o1.x = WlT[4 * YS + t] + LRATE * wacc[4];
    o1.y = WlT[5 * YS + t] + LRATE * wacc[5];
    o1.z = WlT[6 * YS + t] + LRATE * wacc[6];
    o1.w = WlT[7 * YS + t] + LRATE * wacc[7];
    float4* wdst = (float4*)&W[t * Dn + d0];
    wdst[0] = o0; wdst[1] = o1;
  }
}

// ---------------------------------------------------------------------------
// Kernel 6: logits = relu(feats) @ R^T + bias
// ---------------------------------------------------------------------------
__global__ __launch_bounds__(256) void readout_kernel(
    const float* __restrict__ feats, const float* __restrict__ R,
    const float* __restrict__ bias, float* __restrict__ out)
{
  const int g = blockIdx.x * 256 + threadIdx.x;
  if (g >= Bn * On) return;
  const int b = g / On;
  const int o = g - b * On;
  const float* f = feats + b * Hn;
  const float* r = R + o * Hn;
  float acc = bias[o];
#pragma unroll 8
  for (int h = 0; h < Hn; ++h) acc += fmaxf(f[h], 0.f) * r[h];
  out[g] = acc;
}

// ---------------------------------------------------------------------------
extern "C" void kernel_launch(void* const* d_in, const int* in_sizes, int n_in,
                              void* d_out, int out_size, void* d_ws, size_t ws_size,
                              hipStream_t stream) {
  const float* x    = (const float*)d_in[0];  // [2048,784]
  const float* mean = (const float*)d_in[1];  // [784]
  const float* Mw   = (const float*)d_in[2];  // [784,784]
  const float* W0   = (const float*)d_in[3];  // [256,784]
  const float* R    = (const float*)d_in[4];  // [10,256]
  const float* bias = (const float*)d_in[5];  // [10]
  float* out = (float*)d_out;                 // [2048,10]

  float* p = (float*)d_ws;
  float* xw     = p;  p += (size_t)Bn * Dn;        // 1,605,632
  float* feats  = p;  p += (size_t)Bn * Hn;        //   524,288
  float* W_dyn  = p;  p += (size_t)Hn * Dn;        //   200,704
  float* S_all  = p;  p += (size_t)NCHUNK * Cc * Cc; // 131,072
  float* yhat   = p;  p += (size_t)Cc * Hn;        //    16,384
  float* beta_g = p;  p += (size_t)Cc * Cc;        //     4,096
  int*   flag   = (int*)p;                         //         4
  (void)ws_size; (void)n_in; (void)in_sizes; (void)out_size;

  init_flag_kernel<<<1, 1, 0, stream>>>(flag);
  whiten_kernel<<<dim3(Bn / 64, (Dn + 63) / 64), 256, 0, stream>>>(x, mean, Mw, xw);
  sgram_kernel<<<NCHUNK, 256, 0, stream>>>(xw, S_all);
  hipMemcpyAsync(W_dyn, W0, (size_t)Hn * Dn * sizeof(float),
                 hipMemcpyDeviceToDevice, stream);

  for (int c = 0; c < NCHUNK; ++c) {
    const float* xc = xw + (size_t)c * Cc * Dn;
    float* feats_c  = feats + (size_t)c * Cc * Hn;
    yhat_kernel<<<64, 256, 0, stream>>>(xc, W_dyn, yhat);
    seq_kernel<<<256, 256, 0, stream>>>(yhat, S_all + (size_t)c * Cc * Cc,
                                        feats_c, beta_g, flag, c + 1);
    upd_kernel<<<98, 256, 0, stream>>>(xc, feats_c, beta_g, W_dyn);
  }

  readout_kernel<<<(Bn * On + 255) / 256, 256, 0, stream>>>(feats, R, bias, out);
}

// Round 12
// 4838.537 us; speedup vs baseline: 1.0400x; 1.0400x over previous
//
#include <hip/hip_runtime.h>

#define LRATE 1e-3f
static constexpr int Bn = 2048;
static constexpr int Dn = 784;
static constexpr int Hn = 256;
static constexpr int On = 10;
static constexpr int Cc = 64;           // chunk size
static constexpr int NCHUNK = Bn / Cc;  // 32

// LDS row strides (floats): multiples of 4 for aligned float4 (ds_read_b128)
static constexpr int AS = 68;   // 64x64 matrices
static constexpr int YS = 260;  // 64x256 matrices
static constexpr int MSZ = 64 * AS;  // 4352 floats per 64x64 matrix

// 4-lane-group sum via DPP quad_perm (pure VALU; no ds_bpermute)
__device__ __forceinline__ float red4(float s) {
  s += __uint_as_float(__builtin_amdgcn_mov_dpp(__float_as_uint(s), 0xB1, 0xF, 0xF, true)); // xor 1
  s += __uint_as_float(__builtin_amdgcn_mov_dpp(__float_as_uint(s), 0x4E, 0xF, 0xF, true)); // xor 2
  return s;
}

// ---------------------------------------------------------------------------
// Kernel 1: whitening  xw[b,d] = sum_e (x[b,e]-mean[e]) * M[d,e]
// ---------------------------------------------------------------------------
__global__ __launch_bounds__(256) void whiten_kernel(
    const float* __restrict__ x, const float* __restrict__ mean,
    const float* __restrict__ Mw, float* __restrict__ xw)
{
  __shared__ __align__(16) float As[16][64];
  __shared__ __align__(16) float Bs[16][64];
  const int tid = threadIdx.x;
  const int b0 = blockIdx.x * 64;
  const int d0 = blockIdx.y * 64;
  const int mrow = tid >> 2;
  const int kq = (tid & 3) << 2;
  const int ty = tid >> 4, tx = tid & 15;

  float acc[4][4];
#pragma unroll
  for (int i = 0; i < 4; ++i)
#pragma unroll
    for (int j = 0; j < 4; ++j) acc[i][j] = 0.f;

  for (int k0 = 0; k0 < Dn; k0 += 16) {
    __syncthreads();
    {
      const float4 av = *(const float4*)&x[(b0 + mrow) * Dn + k0 + kq];
      const float4 mv = *(const float4*)&mean[k0 + kq];
      As[kq + 0][mrow] = av.x - mv.x;
      As[kq + 1][mrow] = av.y - mv.y;
      As[kq + 2][mrow] = av.z - mv.z;
      As[kq + 3][mrow] = av.w - mv.w;
      float4 bv = make_float4(0.f, 0.f, 0.f, 0.f);
      if (d0 + mrow < Dn) bv = *(const float4*)&Mw[(d0 + mrow) * Dn + k0 + kq];
      Bs[kq + 0][mrow] = bv.x;
      Bs[kq + 1][mrow] = bv.y;
      Bs[kq + 2][mrow] = bv.z;
      Bs[kq + 3][mrow] = bv.w;
    }
    __syncthreads();
#pragma unroll
    for (int k = 0; k < 16; ++k) {
      const float4 a = *(const float4*)&As[k][ty << 2];
      const float4 b = *(const float4*)&Bs[k][tx << 2];
      acc[0][0] += a.x * b.x; acc[0][1] += a.x * b.y; acc[0][2] += a.x * b.z; acc[0][3] += a.x * b.w;
      acc[1][0] += a.y * b.x; acc[1][1] += a.y * b.y; acc[1][2] += a.y * b.z; acc[1][3] += a.y * b.w;
      acc[2][0] += a.z * b.x; acc[2][1] += a.z * b.y; acc[2][2] += a.z * b.z; acc[2][3] += a.z * b.w;
      acc[3][0] += a.w * b.x; acc[3][1] += a.w * b.y; acc[3][2] += a.w * b.z; acc[3][3] += a.w * b.w;
    }
  }
  const int col = d0 + (tx << 2);
  if (col < Dn) {
#pragma unroll
    for (int i = 0; i < 4; ++i) {
      const int row = b0 + (ty << 2) + i;
      *(float4*)&xw[row * Dn + col] =
          make_float4(acc[i][0], acc[i][1], acc[i][2], acc[i][3]);
    }
  }
}

// ---------------------------------------------------------------------------
// Kernel 2: per-chunk Gram blocks  S_c = X_c X_c^T   (all chunks, parallel)
// NOTE: acc[a][b] summation order is identical for (i,j) and (j,i) =>
// S is BIT-EXACTLY symmetric (seq_kernel relies on this for row reads).
// ---------------------------------------------------------------------------
__global__ __launch_bounds__(256) void sgram_kernel(
    const float* __restrict__ xw, float* __restrict__ S_all)
{
  __shared__ __align__(16) float Xs[64 * 396];  // 64 x 392 staged (stride 396)
  const int t = threadIdx.x;
  const int c = blockIdx.x;
  const float* xc = xw + (size_t)c * Cc * Dn;
  const int ti = t >> 4, tj = t & 15;
  float acc[4][4];
#pragma unroll
  for (int a = 0; a < 4; ++a)
#pragma unroll
    for (int b = 0; b < 4; ++b) acc[a][b] = 0.f;

  for (int pass = 0; pass < 2; ++pass) {
    __syncthreads();
    for (int e4 = t; e4 < 64 * 98; e4 += 256) {
      const int r = e4 / 98, c4 = e4 - r * 98;
      *(float4*)&Xs[r * 396 + 4 * c4] =
          *(const float4*)&xc[r * Dn + pass * 392 + 4 * c4];
    }
    __syncthreads();
    for (int k4 = 0; k4 < 98; ++k4) {
      float4 A[4], Bv[4];
#pragma unroll
      for (int a = 0; a < 4; ++a) A[a] = *(const float4*)&Xs[(4 * ti + a) * 396 + 4 * k4];
#pragma unroll
      for (int b = 0; b < 4; ++b) Bv[b] = *(const float4*)&Xs[(4 * tj + b) * 396 + 4 * k4];
#pragma unroll
      for (int a = 0; a < 4; ++a)
#pragma unroll
        for (int b = 0; b < 4; ++b)
          acc[a][b] += A[a].x * Bv[b].x + A[a].y * Bv[b].y + A[a].z * Bv[b].z + A[a].w * Bv[b].w;
    }
  }
  float* Sc = S_all + (size_t)c * Cc * Cc;
#pragma unroll
  for (int a = 0; a < 4; ++a)
#pragma unroll
    for (int b = 0; b < 4; ++b)
      Sc[(4 * ti + a) * Cc + 4 * tj + b] = acc[a][b];
}

// ---------------------------------------------------------------------------
// Kernel 3 (per chunk): yhat[r][h] = sum_d X_c[r][d] * W[h][d]   [64 x 256]
// ---------------------------------------------------------------------------
__global__ __launch_bounds__(256) void yhat_kernel(
    const float* __restrict__ xc, const float* __restrict__ W,
    float* __restrict__ yhat)
{
  const int t = threadIdx.x;
  const int r = t & 63, hh = t >> 6;
  const int h = blockIdx.x * 4 + hh;
  const float4* xr = (const float4*)&xc[r * Dn];
  const float4* wr = (const float4*)&W[h * Dn];
  float acc = 0.f;
#pragma unroll 4
  for (int f = 0; f < 196; ++f) {
    const float4 a = xr[f], b = wr[f];
    acc += a.x * b.x + a.y * b.y + a.z * b.z + a.w * b.w;
  }
  yhat[r * Hn + h] = acc;
}

// ---------------------------------------------------------------------------
// Kernel 4 (per chunk): 64-step recurrence, BLOCKED by R=4.
// Same real arithmetic as the round-10-passing version. This round adds
// TRIANGULAR-WIDTH dots: all state matrices (Gy/AlT/BeT/GuT rows, VMb) are
// zero in columns >= b0, so ph1a/ph1b/ph4 dots read only wseg = ceil(b0/16)
// float4 segments per lane (lane qr covers [4*wseg*qr, 4*wseg*(qr+1))).
// Average LDS-read + FMA work in those phases drops ~42%; block 0 is ~free.
// Loops are predicated-unrolled (wave-uniform wseg) -> static reg indexing.
// ---------------------------------------------------------------------------
__global__ __launch_bounds__(256, 1) void seq_kernel(
    const float* __restrict__ yhat_g, const float* __restrict__ S_g,
    float* __restrict__ feats_c, float* __restrict__ beta_g)
{
  __shared__ __align__(16) float lds[8 * MSZ + 1872];  // 146,752 B
  float* Gy  = lds + 0 * MSZ;
  float* AlT = lds + 1 * MSZ;
  float* BeT = lds + 2 * MSZ;
  float* GuT = lds + 3 * MSZ;
  float* Qs  = lds + 4 * MSZ;
  float* Ts  = lds + 5 * MSZ;
  float* Ss  = lds + 6 * MSZ;
  float* Al  = lds + 7 * MSZ;
  float* VOb = lds + 8 * MSZ;        // [4][AS] (row-major by s, for ph1b dots)
  float* VMb = VOb + 4 * AS;         // [4][AS], zeroed at block positions
  float* GVo = VMb + 4 * AS;         // [16]:  GVo[s'*4 + s]
  float* Pk  = GVo + 16;             // [64][20]: og[4]|oq[4]|oa[4]|vo[4]|pad
  // epilogue stages yh (16640 floats) over Gy..GuT (17408); Ts/Ss/Al intact.

  const int t = threadIdx.x;
  const int k = t >> 2, qr = t & 3;
  const int m0q = qr * 16;

  // ---- prologue: zero Gy,AlT,BeT,GuT,Qs (contiguous 5*MSZ) ----
  for (int e4 = t; e4 < 5 * MSZ / 4; e4 += 256)
    *(float4*)&lds[4 * e4] = make_float4(0.f, 0.f, 0.f, 0.f);
  // Ss <- S_g (rows stride AS)
  for (int e4 = t; e4 < 1024; e4 += 256) {
    const int r = e4 >> 4, c4 = e4 & 15;
    *(float4*)&Ss[r * AS + 4 * c4] = ((const float4*)S_g)[e4];
  }
  // Ts = yhat yhat^T from global (16x16 grid, 4x4 blocks) — bit-symmetric
  {
    const int ti = t >> 4, tj = t & 15;
    float acc[4][4];
#pragma unroll
    for (int a = 0; a < 4; ++a)
#pragma unroll
      for (int b = 0; b < 4; ++b) acc[a][b] = 0.f;
    for (int k4 = 0; k4 < 64; ++k4) {
      float4 A[4], Bv[4];
#pragma unroll
      for (int a = 0; a < 4; ++a) A[a] = *(const float4*)&yhat_g[(4 * ti + a) * Hn + 4 * k4];
#pragma unroll
      for (int b = 0; b < 4; ++b) Bv[b] = *(const float4*)&yhat_g[(4 * tj + b) * Hn + 4 * k4];
#pragma unroll
      for (int a = 0; a < 4; ++a)
#pragma unroll
        for (int b = 0; b < 4; ++b)
          acc[a][b] += A[a].x * Bv[b].x + A[a].y * Bv[b].y + A[a].z * Bv[b].z + A[a].w * Bv[b].w;
    }
#pragma unroll
    for (int a = 0; a < 4; ++a)
#pragma unroll
      for (int b = 0; b < 4; ++b)
        Ts[(4 * ti + a) * AS + 4 * tj + b] = acc[a][b];
  }
  __syncthreads();

  __builtin_amdgcn_s_setprio(1);

  for (int b = 0; b < Cc / 4; ++b) {
    const int b0 = 4 * b;
    const int wseg = (b0 + 15) >> 4;   // 0..4, wave-uniform
    const int o4 = qr * wseg;          // lane's first float4 index in a row

    // ================= ph1a: outer dots (triangular width) =================
    float4 gyS[4], atS[4], qS[4];
    {
      const float4* gyp = (const float4*)&Gy[k * AS] + o4;
      const float4* atp = (const float4*)&AlT[k * AS] + o4;
      const float4* qp  = (const float4*)&Qs[k * AS] + o4;
#pragma unroll
      for (int f = 0; f < 4; ++f)
        if (f < wseg) { gyS[f] = gyp[f]; atS[f] = atp[f]; qS[f] = qp[f]; }
    }
    float og[4], oq[4], oa[4], grow[4];
#pragma unroll
    for (int s = 0; s < 4; ++s) {
      const float4* pR = (const float4*)&GuT[(b0 + s) * AS] + o4;
      float g0 = 0.f, g1 = 0.f, g2 = 0.f, g3 = 0.f;
      float a0 = 0.f, a1 = 0.f, a2 = 0.f, a3 = 0.f;
      float w0 = 0.f, w1 = 0.f, w2 = 0.f, w3 = 0.f;
#pragma unroll
      for (int f = 0; f < 4; ++f)
        if (f < wseg) {
          const float4 p = pR[f];
          g0 += p.x * gyS[f].x; g1 += p.y * gyS[f].y; g2 += p.z * gyS[f].z; g3 += p.w * gyS[f].w;
          a0 += p.x * atS[f].x; a1 += p.y * atS[f].y; a2 += p.z * atS[f].z; a3 += p.w * atS[f].w;
          w0 += p.x * qS[f].x;  w1 += p.y * qS[f].y;  w2 += p.z * qS[f].z;  w3 += p.w * qS[f].w;
        }
      og[s] = red4((g0 + g1) + (g2 + g3));
      oa[s] = red4((a0 + a1) + (a2 + a3));
      oq[s] = red4((w0 + w1) + (w2 + w3));
      grow[s] = Gy[(b0 + s) * AS + k];
    }
    if (qr == 0)      *(float4*)&Pk[k * 20 + 0] = make_float4(og[0], og[1], og[2], og[3]);
    else if (qr == 1) *(float4*)&Pk[k * 20 + 4] = make_float4(oq[0], oq[1], oq[2], oq[3]);
    else if (qr == 2) *(float4*)&Pk[k * 20 + 8] = make_float4(oa[0], oa[1], oa[2], oa[3]);
    else {
      float vo[4];
#pragma unroll
      for (int s = 0; s < 4; ++s) vo[s] = grow[s] + LRATE * oq[s];
      *(float4*)&Pk[k * 20 + 12] = make_float4(vo[0], vo[1], vo[2], vo[3]);
#pragma unroll
      for (int s = 0; s < 4; ++s) VOb[s * AS + k] = vo[s];
    }
    __syncthreads();

    // ================= ph1b: GVo pair dots (bounded by Gu's zero cols) =====
    if (t < 64) {
      const int pr = t >> 2;          // 0..15: s' = pr>>2, s = pr&3
      const int sp = pr >> 2, s2 = pr & 3;
      const int q2 = t & 3;
      const float4* gr = (const float4*)&GuT[(b0 + sp) * AS] + q2 * wseg;
      const float4* vr = (const float4*)&VOb[s2 * AS] + q2 * wseg;
      float d0 = 0.f, d1 = 0.f, d2 = 0.f, d3 = 0.f;
#pragma unroll
      for (int f = 0; f < 4; ++f)
        if (f < wseg) {
          const float4 g = gr[f], v = vr[f];
          d0 += g.x * v.x; d1 += g.y * v.y; d2 += g.z * v.z; d3 += g.w * v.w;
        }
      const float d = red4((d0 + d1) + (d2 + d3));
      if (q2 == 0) GVo[pr] = d;
    }
    __syncthreads();

    // ================= ph2: redundant 4x4 inner solve =================
    float T8[4][4], S8v[4][4], OG8[4][4], OQ8[4][4], GV8[4][4];
#pragma unroll
    for (int j = 0; j < 4; ++j) {
      const float4 t4 = *(const float4*)&Ts[(b0 + j) * AS + b0];  // T row (sym)
      T8[j][0] = t4.x; T8[j][1] = t4.y; T8[j][2] = t4.z; T8[j][3] = t4.w;
      const float4 s4 = *(const float4*)&Ss[(b0 + j) * AS + b0];  // S row (sym)
      S8v[j][0] = s4.x; S8v[j][1] = s4.y; S8v[j][2] = s4.z; S8v[j][3] = s4.w;
      const float4 g4 = *(const float4*)&Pk[(b0 + j) * 20 + 0];   // og col j
      OG8[0][j] = g4.x; OG8[1][j] = g4.y; OG8[2][j] = g4.z; OG8[3][j] = g4.w;
      const float4 q4 = *(const float4*)&Pk[(b0 + j) * 20 + 4];   // oq col j
      OQ8[0][j] = q4.x; OQ8[1][j] = q4.y; OQ8[2][j] = q4.z; OQ8[3][j] = q4.w;
      const float4 v4 = ((const float4*)GVo)[j];
      GV8[j][0] = v4.x; GV8[j][1] = v4.y; GV8[j][2] = v4.z; GV8[j][3] = v4.w;
    }
    float G8[4][4], V8[4][4], U8[4][4], W8[4][4], Qd[4];
    // s = 0
#pragma unroll
    for (int j = 0; j < 4; ++j) {
      G8[0][j] = T8[0][j] + LRATE * OG8[0][j];
      V8[0][j] = 0.f;
      W8[j][0] = GV8[j][0];
    }
#pragma unroll
    for (int j = 0; j < 4; ++j) U8[0][j] = S8v[0][j] - G8[0][j] - LRATE * W8[j][0];
    Qd[0] = G8[0][0] + LRATE * W8[0][0];
    // s = 1
    {
      const float p0 = U8[0][1];
#pragma unroll
      for (int j = 0; j < 4; ++j) G8[1][j] = T8[1][j] + LRATE * (OG8[1][j] + p0 * G8[0][j]);
      V8[1][0] = G8[0][1] + LRATE * (OQ8[1][0] + p0 * Qd[0]);
      V8[1][1] = V8[1][2] = V8[1][3] = 0.f;
#pragma unroll
      for (int j = 0; j < 4; ++j) W8[j][1] = GV8[j][1] + LRATE * (p0 * W8[j][0]);
#pragma unroll
      for (int j = 0; j < 4; ++j)
        U8[1][j] = S8v[1][j] - G8[1][j] - LRATE * (W8[j][1] + V8[1][0] * U8[0][j]);
      Qd[1] = G8[1][1] + LRATE * (W8[1][1] + p0 * V8[1][0]);
    }
    // s = 2
    {
      const float p0 = U8[0][2], p1 = U8[1][2];
#pragma unroll
      for (int j = 0; j < 4; ++j)
        G8[2][j] = T8[2][j] + LRATE * (OG8[2][j] + p0 * G8[0][j] + p1 * G8[1][j]);
      V8[2][0] = G8[0][2] + LRATE * (OQ8[2][0] + p0 * Qd[0] + p1 * V8[1][0]);
      V8[2][1] = G8[1][2] + LRATE * (OQ8[2][1] + p1 * Qd[1]);  // p0*V8[0][1] = 0
      V8[2][2] = V8[2][3] = 0.f;
#pragma unroll
      for (int j = 0; j < 4; ++j) W8[j][2] = GV8[j][2] + LRATE * (p0 * W8[j][0] + p1 * W8[j][1]);
#pragma unroll
      for (int j = 0; j < 4; ++j)
        U8[2][j] = S8v[2][j] - G8[2][j] -
                   LRATE * (W8[j][2] + V8[2][0] * U8[0][j] + V8[2][1] * U8[1][j]);
      Qd[2] = G8[2][2] + LRATE * (W8[2][2] + p0 * V8[2][0] + p1 * V8[2][1]);
    }
    // s = 3
    {
      const float p0 = U8[0][3], p1 = U8[1][3], p2 = U8[2][3];
#pragma unroll
      for (int j = 0; j < 4; ++j)
        G8[3][j] = T8[3][j] + LRATE * (OG8[3][j] + p0 * G8[0][j] + p1 * G8[1][j] + p2 * G8[2][j]);
      V8[3][0] = G8[0][3] + LRATE * (OQ8[3][0] + p0 * Qd[0] + p1 * V8[1][0] + p2 * V8[2][0]);
      V8[3][1] = G8[1][3] + LRATE * (OQ8[3][1] + p1 * Qd[1] + p2 * V8[2][1]);
      V8[3][2] = G8[2][3] + LRATE * (OQ8[3][2] + p2 * Qd[2]);
      V8[3][3] = 0.f;
#pragma unroll
      for (int j = 0; j < 4; ++j)
        W8[j][3] = GV8[j][3] + LRATE * (p0 * W8[j][0] + p1 * W8[j][1] + p2 * W8[j][2]);
#pragma unroll
      for (int j = 0; j < 4; ++j)
        U8[3][j] = S8v[3][j] - G8[3][j] -
                   LRATE * (W8[j][3] + V8[3][0] * U8[0][j] + V8[3][1] * U8[1][j] +
                            V8[3][2] * U8[2][j]);
      Qd[3] = G8[3][3] + LRATE * (W8[3][3] + p0 * V8[3][0] + p1 * V8[3][1] + p2 * V8[3][2]);
    }

    // ================= ph3: per-thread triangular expansion =================
    float TsK[4], OGk[4], OAk[4], VOk[4];
    {
      const float4 tk4 = *(const float4*)&Ts[k * AS + b0];    // Ts sym row read
      TsK[0] = tk4.x; TsK[1] = tk4.y; TsK[2] = tk4.z; TsK[3] = tk4.w;
      const float4 og4 = *(const float4*)&Pk[k * 20 + 0];
      OGk[0] = og4.x; OGk[1] = og4.y; OGk[2] = og4.z; OGk[3] = og4.w;
      const float4 oa4 = *(const float4*)&Pk[k * 20 + 8];
      OAk[0] = oa4.x; OAk[1] = oa4.y; OAk[2] = oa4.z; OAk[3] = oa4.w;
      const float4 vo4 = *(const float4*)&Pk[k * 20 + 12];
      VOk[0] = vo4.x; VOk[1] = vo4.y; VOk[2] = vo4.z; VOk[3] = vo4.w;
    }
    float gy[4], aI[4], vm[4];
    // s=0
    gy[0] = TsK[0] + LRATE * OGk[0];
    { const float a = LRATE * OAk[0]; aI[0] = (k < b0) ? a : ((k == b0) ? 1.f : 0.f); }
    vm[0] = (k < b0) ? VOk[0] : 0.f;
    // s=1
    {
      const float p0 = U8[0][1];
      gy[1] = TsK[1] + LRATE * (OGk[1] + p0 * gy[0]);
      const float a = LRATE * (OAk[1] + p0 * aI[0]);
      aI[1] = (k < b0 + 1) ? a : ((k == b0 + 1) ? 1.f : 0.f);
      const float vt0 = (k == b0) ? Qd[0] : vm[0];
      float v = VOk[1] + LRATE * (p0 * vt0);
      if (k == b0) v += G8[0][1];
      vm[1] = (k < b0 + 1) ? v : 0.f;
    }
    // s=2
    {
      const float p0 = U8[0][2], p1 = U8[1][2];
      gy[2] = TsK[2] + LRATE * (OGk[2] + p0 * gy[0] + p1 * gy[1]);
      const float a = LRATE * (OAk[2] + p0 * aI[0] + p1 * aI[1]);
      aI[2] = (k < b0 + 2) ? a : ((k == b0 + 2) ? 1.f : 0.f);
      const float vt0 = (k == b0) ? Qd[0] : vm[0];
      const float vt1 = (k == b0 + 1) ? Qd[1] : vm[1];
      float v = VOk[2] + LRATE * (p0 * vt0 + p1 * vt1);
      if (k == b0) v += G8[0][2];
      else if (k == b0 + 1) v += G8[1][2];
      vm[2] = (k < b0 + 2) ? v : 0.f;
    }
    // s=3
    {
      const float p0 = U8[0][3], p1 = U8[1][3], p2 = U8[2][3];
      gy[3] = TsK[3] + LRATE * (OGk[3] + p0 * gy[0] + p1 * gy[1] + p2 * gy[2]);
      const float a = LRATE * (OAk[3] + p0 * aI[0] + p1 * aI[1] + p2 * aI[2]);
      aI[3] = (k < b0 + 3) ? a : ((k == b0 + 3) ? 1.f : 0.f);
      const float vt0 = (k == b0) ? Qd[0] : vm[0];
      const float vt1 = (k == b0 + 1) ? Qd[1] : vm[1];
      const float vt2 = (k == b0 + 2) ? Qd[2] : vm[2];
      float v = VOk[3] + LRATE * (p0 * vt0 + p1 * vt1 + p2 * vt2);
      if (k == b0) v += G8[0][3];
      else if (k == b0 + 1) v += G8[1][3];
      else if (k == b0 + 2) v += G8[2][3];
      vm[3] = (k < b0 + 3) ? v : 0.f;
    }
    // Q writes carry Qd at the diagonal from every writer (race-safe: all
    // writers store the same value). qw[s] = (k==b0+s) ? Qd[s] : vm[s].
    float qw[4];
#pragma unroll
    for (int s = 0; s < 4; ++s) qw[s] = (k == b0 + s) ? Qd[s] : vm[s];
    if (qr == 0) {
      *(float4*)&Gy[k * AS + b0] = make_float4(gy[0], gy[1], gy[2], gy[3]);
#pragma unroll
      for (int s = 0; s < 4; ++s) Qs[(b0 + s) * AS + k] = qw[s];
    } else if (qr == 1) {
      *(float4*)&AlT[k * AS + b0] = make_float4(aI[0], aI[1], aI[2], aI[3]);
      *(float4*)&Qs[k * AS + b0] = make_float4(qw[0], qw[1], qw[2], qw[3]);
    } else if (qr == 2) {
#pragma unroll
      for (int s = 0; s < 4; ++s) Al[(b0 + s) * AS + k] = aI[s];
#pragma unroll
      for (int s = 0; s < 4; ++s) VMb[s * AS + k] = (k < b0) ? vm[s] : 0.f;
    }
    __syncthreads();

    // ================= ph4: b / gu (triangular width) =================
    float4 beS[4], guS[4];
    {
      const float4* bep = (const float4*)&BeT[k * AS] + o4;
      const float4* gup = (const float4*)&GuT[k * AS] + o4;
#pragma unroll
      for (int f = 0; f < 4; ++f)
        if (f < wseg) { beS[f] = bep[f]; guS[f] = gup[f]; }
    }
    float bO[4], gO[4];
#pragma unroll
    for (int s = 0; s < 4; ++s) {
      const float4* vmr = (const float4*)&VMb[s * AS] + o4;
      float b0a = 0.f, b1a = 0.f, b2a = 0.f, b3a = 0.f;
      float u0 = 0.f, u1 = 0.f, u2 = 0.f, u3 = 0.f;
#pragma unroll
      for (int f = 0; f < 4; ++f)
        if (f < wseg) {
          const float4 v = vmr[f];
          b0a += v.x * beS[f].x; b1a += v.y * beS[f].y; b2a += v.z * beS[f].z; b3a += v.w * beS[f].w;
          u0 += v.x * guS[f].x; u1 += v.y * guS[f].y; u2 += v.z * guS[f].z; u3 += v.w * guS[f].w;
        }
      bO[s] = red4((b0a + b1a) + (b2a + b3a));
      gO[s] = red4((u0 + u1) + (u2 + u3));
    }
    float SsK[4];
    {
      const float4 sk4 = *(const float4*)&Ss[k * AS + b0];    // Ss sym row read
      SsK[0] = sk4.x; SsK[1] = sk4.y; SsK[2] = sk4.z; SsK[3] = sk4.w;
    }
    float bI[4], gu[4];
    {
      const float bb = -LRATE * bO[0];
      bI[0] = (k < b0) ? bb : ((k == b0) ? 1.f : 0.f);
      gu[0] = SsK[0] - gy[0] - LRATE * gO[0];
    }
    {
      const float bb = -LRATE * (bO[1] + V8[1][0] * bI[0]);
      bI[1] = (k < b0 + 1) ? bb : ((k == b0 + 1) ? 1.f : 0.f);
      gu[1] = SsK[1] - gy[1] - LRATE * (gO[1] + V8[1][0] * gu[0]);
    }
    {
      const float bb = -LRATE * (bO[2] + V8[2][0] * bI[0] + V8[2][1] * bI[1]);
      bI[2] = (k < b0 + 2) ? bb : ((k == b0 + 2) ? 1.f : 0.f);
      gu[2] = SsK[2] - gy[2] - LRATE * (gO[2] + V8[2][0] * gu[0] + V8[2][1] * gu[1]);
    }
    {
      const float bb = -LRATE * (bO[3] + V8[3][0] * bI[0] + V8[3][1] * bI[1] + V8[3][2] * bI[2]);
      bI[3] = (k < b0 + 3) ? bb : ((k == b0 + 3) ? 1.f : 0.f);
      gu[3] = SsK[3] - gy[3] -
              LRATE * (gO[3] + V8[3][0] * gu[0] + V8[3][1] * gu[1] + V8[3][2] * gu[2]);
    }
    if (qr == 0) {
      *(float4*)&GuT[k * AS + b0] = make_float4(gu[0], gu[1], gu[2], gu[3]);
    } else if (qr == 1) {
      *(float4*)&BeT[k * AS + b0] = make_float4(bI[0], bI[1], bI[2], bI[3]);
    }
    __syncthreads();
  }

  __builtin_amdgcn_s_setprio(0);

  // ---- epilogue 1: beta export (transpose from BeT; row-major beta_g) ----
  {
    const int r = t >> 2, q = t & 3;
#pragma unroll
    for (int kk = 0; kk < 16; ++kk) {
      const int kcol = q * 16 + kk;
      beta_g[r * 64 + kcol] = BeT[kcol * AS + r];
    }
  }
  __syncthreads();

  // ---- epilogue 2: stage yh over Gy..GuT (stride YS); Ts/Ss/Al untouched ----
  for (int e4 = t; e4 < 4096; e4 += 256) {
    const int r = e4 >> 6, c4 = e4 & 63;
    *(float4*)&lds[r * YS + 4 * c4] = ((const float4*)yhat_g)[e4];
  }
  __syncthreads();

  // ---- epilogue 3: feats = alpha * yh (alpha rows from Al) ----
  {
    const int r = k;  // t>>2
    const int m0q4 = m0q * 4;
    float a[64];
#pragma unroll
    for (int f = 0; f < 16; ++f) {
      const float4 av = *(const float4*)&Al[r * AS + 4 * f];
      a[4 * f + 0] = av.x; a[4 * f + 1] = av.y;
      a[4 * f + 2] = av.z; a[4 * f + 3] = av.w;
    }
    float4 acc[16];
#pragma unroll
    for (int f = 0; f < 16; ++f) acc[f] = make_float4(0.f, 0.f, 0.f, 0.f);
#pragma unroll
    for (int m4 = 0; m4 < 16; ++m4) {
      const float av0 = a[4 * m4 + 0], av1 = a[4 * m4 + 1];
      const float av2 = a[4 * m4 + 2], av3 = a[4 * m4 + 3];
      const float4* y0 = (const float4*)&lds[(4 * m4 + 0) * YS + m0q4];
      const float4* y1 = (const float4*)&lds[(4 * m4 + 1) * YS + m0q4];
      const float4* y2 = (const float4*)&lds[(4 * m4 + 2) * YS + m0q4];
      const float4* y3 = (const float4*)&lds[(4 * m4 + 3) * YS + m0q4];
#pragma unroll
      for (int f = 0; f < 16; ++f) {
        const float4 z0 = y0[f], z1 = y1[f], z2 = y2[f], z3 = y3[f];
        acc[f].x += av0 * z0.x + av1 * z1.x + av2 * z2.x + av3 * z3.x;
        acc[f].y += av0 * z0.y + av1 * z1.y + av2 * z2.y + av3 * z3.y;
        acc[f].z += av0 * z0.z + av1 * z1.z + av2 * z2.z + av3 * z3.z;
        acc[f].w += av0 * z0.w + av1 * z1.w + av2 * z2.w + av3 * z3.w;
      }
    }
    float4* dst = (float4*)&feats_c[r * Hn + m0q4];
#pragma unroll
    for (int f = 0; f < 16; ++f) dst[f] = acc[f];
  }
}

// ---------------------------------------------------------------------------
// Kernel 5 (per chunk): V = X_c - Y W ; U = beta V ; W += LR * Y^T U.
// grid 98 WGs, each owns 8 consecutive W columns.
// ---------------------------------------------------------------------------
__global__ __launch_bounds__(256, 1) void upd_kernel(
    const float* __restrict__ xc, const float* __restrict__ Yg,
    const float* __restrict__ beta_g, float* __restrict__ W)
{
  __shared__ __align__(16) float Yl[64 * YS];
  __shared__ __align__(16) float bl[64 * AS];
  __shared__ __align__(16) float WlT[8 * YS];
  __shared__ __align__(16) float XT[8 * 64];
  __shared__ __align__(16) float VT[8 * 64];
  __shared__ __align__(16) float UT[8 * 64];
  const int t = threadIdx.x;
  const int d0 = blockIdx.x * 8;

  {  // load Y
    const int r = t >> 2, qr = t & 3;
    const float4* src = (const float4*)&Yg[r * Hn + qr * 64];
    float4* dst = (float4*)&Yl[r * YS + qr * 64];
#pragma unroll
    for (int f = 0; f < 16; ++f) dst[f] = src[f];
  }
#pragma unroll
  for (int f = 0; f < 4; ++f) {  // load beta
    const int e4 = t + 256 * f;
    const int r = e4 >> 4, c4 = e4 & 15;
    *(float4*)&bl[r * AS + 4 * c4] = ((const float4*)beta_g)[e4];
  }
  {  // load W slice (transposed)
    const float4* wsrc = (const float4*)&W[t * Dn + d0];
    const float4 w0 = wsrc[0], w1 = wsrc[1];
    WlT[0 * YS + t] = w0.x; WlT[1 * YS + t] = w0.y; WlT[2 * YS + t] = w0.z; WlT[3 * YS + t] = w0.w;
    WlT[4 * YS + t] = w1.x; WlT[5 * YS + t] = w1.y; WlT[6 * YS + t] = w1.z; WlT[7 * YS + t] = w1.w;
  }
  if (t < 64) {  // load X slice (transposed)
    const float4* xsrc = (const float4*)&xc[t * Dn + d0];
    const float4 x0 = xsrc[0], x1 = xsrc[1];
    XT[0 * 64 + t] = x0.x; XT[1 * 64 + t] = x0.y; XT[2 * 64 + t] = x0.z; XT[3 * 64 + t] = x0.w;
    XT[4 * 64 + t] = x1.x; XT[5 * 64 + t] = x1.y; XT[6 * 64 + t] = x1.z; XT[7 * 64 + t] = x1.w;
  }
  __syncthreads();
  const int r = t & 63, da = t >> 6, db = da + 4;
  {  // V = X - Y W
    float va = XT[da * 64 + r], vb = XT[db * 64 + r];
    const float4* yrow = (const float4*)&Yl[r * YS];
    const float4* wa = (const float4*)&WlT[da * YS];
    const float4* wb = (const float4*)&WlT[db * YS];
#pragma unroll 8
    for (int f = 0; f < 64; ++f) {
      const float4 y = yrow[f], A = wa[f], Bv = wb[f];
      va -= y.x * A.x + y.y * A.y + y.z * A.z + y.w * A.w;
      vb -= y.x * Bv.x + y.y * Bv.y + y.z * Bv.z + y.w * Bv.w;
    }
    VT[da * 64 + r] = va; VT[db * 64 + r] = vb;
  }
  __syncthreads();
  {  // U = beta V
    float ua = 0.f, ub = 0.f;
    const float4* br = (const float4*)&bl[r * AS];
    const float4* vta = (const float4*)&VT[da * 64];
    const float4* vtb = (const float4*)&VT[db * 64];
#pragma unroll
    for (int f = 0; f < 16; ++f) {
      const float4 b = br[f], A = vta[f], Bv = vtb[f];
      ua += b.x * A.x + b.y * A.y + b.z * A.z + b.w * A.w;
      ub += b.x * Bv.x + b.y * Bv.y + b.z * Bv.z + b.w * Bv.w;
    }
    UT[da * 64 + r] = ua; UT[db * 64 + r] = ub;
  }
  __syncthreads();
  {  // W[h=t][d0+dj] += LR * sum_r Y[r][h] * U[r][dj]
    float wacc[8];
#pragma unroll
    for (int dj = 0; dj < 8; ++dj) wacc[dj] = 0.f;
    for (int r4 = 0; r4 < 16; ++r4) {
      float4 u[8];
#pragma unroll
      for (int dj = 0; dj < 8; ++dj) u[dj] = *(const float4*)&UT[dj * 64 + 4 * r4];
      const float y0 = Yl[(4 * r4 + 0) * YS + t];
      const float y1 = Yl[(4 * r4 + 1) * YS + t];
      const float y2 = Yl[(4 * r4 + 2) * YS + t];
      const float y3 = Yl[(4 * r4 + 3) * YS + t];
#pragma unroll
      for (int dj = 0; dj < 8; ++dj)
        wacc[dj] += y0 * u[dj].x + y1 * u[dj].y + y2 * u[dj].z + y3 * u[dj].w;
    }
    float4 o0, o1;
    o0.x = WlT[0 * YS + t] + LRATE * wacc[0];
    o0.y = WlT[1 * YS + t] + LRATE * wacc[1];
    o0.z = WlT[2 * YS + t] + LRATE * wacc[2];
    o0.w = WlT[3 * YS + t] + LRATE * wacc[3];
    o1.x = WlT[4 * YS + t] + LRATE * wacc[4];
    o1.y = WlT[5 * YS + t] + LRATE * wacc[5];
    o1.z = WlT[6 * YS + t] + LRATE * wacc[6];
    o1.w = WlT[7 * YS + t] + LRATE * wacc[7];
    float4* wdst = (float4*)&W[t * Dn + d0];
    wdst[0] = o0; wdst[1] = o1;
  }
}

// ---------------------------------------------------------------------------
// Kernel 6: logits = relu(feats) @ R^T + bias
// ---------------------------------------------------------------------------
__global__ __launch_bounds__(256) void readout_kernel(
    const float* __restrict__ feats, const float* __restrict__ R,
    const float* __restrict__ bias, float* __restrict__ out)
{
  const int g = blockIdx.x * 256 + threadIdx.x;
  if (g >= Bn * On) return;
  const int b = g / On;
  const int o = g - b * On;
  const float* f = feats + b * Hn;
  const float* r = R + o * Hn;
  float acc = bias[o];
#pragma unroll 8
  for (int h = 0; h < Hn; ++h) acc += fmaxf(f[h], 0.f) * r[h];
  out[g] = acc;
}

// ---------------------------------------------------------------------------
extern "C" void kernel_launch(void* const* d_in, const int* in_sizes, int n_in,
                              void* d_out, int out_size, void* d_ws, size_t ws_size,
                              hipStream_t stream) {
  const float* x    = (const float*)d_in[0];  // [2048,784]
  const float* mean = (const float*)d_in[1];  // [784]
  const float* Mw   = (const float*)d_in[2];  // [784,784]
  const float* W0   = (const float*)d_in[3];  // [256,784]
  const float* R    = (const float*)d_in[4];  // [10,256]
  const float* bias = (const float*)d_in[5];  // [10]
  float* out = (float*)d_out;                 // [2048,10]

  float* p = (float*)d_ws;
  float* xw     = p;  p += (size_t)Bn * Dn;        // 1,605,632
  float* feats  = p;  p += (size_t)Bn * Hn;        //   524,288
  float* W_dyn  = p;  p += (size_t)Hn * Dn;        //   200,704
  float* S_all  = p;  p += (size_t)NCHUNK * Cc * Cc; // 131,072
  float* yhat   = p;  p += (size_t)Cc * Hn;        //    16,384
  float* beta_g = p;  p += (size_t)Cc * Cc;        //     4,096
  (void)ws_size; (void)n_in; (void)in_sizes; (void)out_size;

  whiten_kernel<<<dim3(Bn / 64, (Dn + 63) / 64), 256, 0, stream>>>(x, mean, Mw, xw);
  sgram_kernel<<<NCHUNK, 256, 0, stream>>>(xw, S_all);
  hipMemcpyAsync(W_dyn, W0, (size_t)Hn * Dn * sizeof(float),
                 hipMemcpyDeviceToDevice, stream);

  for (int c = 0; c < NCHUNK; ++c) {
    const float* xc = xw + (size_t)c * Cc * Dn;
    float* feats_c  = feats + (size_t)c * Cc * Hn;
    yhat_kernel<<<64, 256, 0, stream>>>(xc, W_dyn, yhat);
    seq_kernel<<<1, 256, 0, stream>>>(yhat, S_all + (size_t)c * Cc * Cc,
                                      feats_c, beta_g);
    upd_kernel<<<98, 256, 0, stream>>>(xc, feats_c, beta_g, W_dyn);
  }

  readout_kernel<<<(Bn * On + 255) / 256, 256, 0, stream>>>(feats, R, bias, out);
}

// Round 13
// 3995.331 us; speedup vs baseline: 1.2594x; 1.2110x over previous
//
#include <hip/hip_runtime.h>

#define LRATE 1e-3f
static constexpr int Bn = 2048;
static constexpr int Dn = 784;
static constexpr int Hn = 256;
static constexpr int On = 10;
static constexpr int Cc = 64;           // chunk size
static constexpr int NCHUNK = Bn / Cc;  // 32

// LDS row strides (floats): multiples of 4 for aligned float4 (ds_read_b128)
static constexpr int AS = 68;   // 64x64 matrices
static constexpr int YS = 260;  // 64x256 matrices
static constexpr int MSZ = 64 * AS;  // 4352 floats per 64x64 matrix

// 4-lane-group sum via DPP quad_perm (pure VALU; no ds_bpermute)
__device__ __forceinline__ float red4(float s) {
  s += __uint_as_float(__builtin_amdgcn_mov_dpp(__float_as_uint(s), 0xB1, 0xF, 0xF, true)); // xor 1
  s += __uint_as_float(__builtin_amdgcn_mov_dpp(__float_as_uint(s), 0x4E, 0xF, 0xF, true)); // xor 2
  return s;
}

// ---------------------------------------------------------------------------
// Kernel 1: whitening  xw[b,d] = sum_e (x[b,e]-mean[e]) * M[d,e]
// ---------------------------------------------------------------------------
__global__ __launch_bounds__(256) void whiten_kernel(
    const float* __restrict__ x, const float* __restrict__ mean,
    const float* __restrict__ Mw, float* __restrict__ xw)
{
  __shared__ __align__(16) float As[16][64];
  __shared__ __align__(16) float Bs[16][64];
  const int tid = threadIdx.x;
  const int b0 = blockIdx.x * 64;
  const int d0 = blockIdx.y * 64;
  const int mrow = tid >> 2;
  const int kq = (tid & 3) << 2;
  const int ty = tid >> 4, tx = tid & 15;

  float acc[4][4];
#pragma unroll
  for (int i = 0; i < 4; ++i)
#pragma unroll
    for (int j = 0; j < 4; ++j) acc[i][j] = 0.f;

  for (int k0 = 0; k0 < Dn; k0 += 16) {
    __syncthreads();
    {
      const float4 av = *(const float4*)&x[(b0 + mrow) * Dn + k0 + kq];
      const float4 mv = *(const float4*)&mean[k0 + kq];
      As[kq + 0][mrow] = av.x - mv.x;
      As[kq + 1][mrow] = av.y - mv.y;
      As[kq + 2][mrow] = av.z - mv.z;
      As[kq + 3][mrow] = av.w - mv.w;
      float4 bv = make_float4(0.f, 0.f, 0.f, 0.f);
      if (d0 + mrow < Dn) bv = *(const float4*)&Mw[(d0 + mrow) * Dn + k0 + kq];
      Bs[kq + 0][mrow] = bv.x;
      Bs[kq + 1][mrow] = bv.y;
      Bs[kq + 2][mrow] = bv.z;
      Bs[kq + 3][mrow] = bv.w;
    }
    __syncthreads();
#pragma unroll
    for (int k = 0; k < 16; ++k) {
      const float4 a = *(const float4*)&As[k][ty << 2];
      const float4 b = *(const float4*)&Bs[k][tx << 2];
      acc[0][0] += a.x * b.x; acc[0][1] += a.x * b.y; acc[0][2] += a.x * b.z; acc[0][3] += a.x * b.w;
      acc[1][0] += a.y * b.x; acc[1][1] += a.y * b.y; acc[1][2] += a.y * b.z; acc[1][3] += a.y * b.w;
      acc[2][0] += a.z * b.x; acc[2][1] += a.z * b.y; acc[2][2] += a.z * b.z; acc[2][3] += a.z * b.w;
      acc[3][0] += a.w * b.x; acc[3][1] += a.w * b.y; acc[3][2] += a.w * b.z; acc[3][3] += a.w * b.w;
    }
  }
  const int col = d0 + (tx << 2);
  if (col < Dn) {
#pragma unroll
    for (int i = 0; i < 4; ++i) {
      const int row = b0 + (ty << 2) + i;
      *(float4*)&xw[row * Dn + col] =
          make_float4(acc[i][0], acc[i][1], acc[i][2], acc[i][3]);
    }
  }
}

// ---------------------------------------------------------------------------
// Kernel 2: per-chunk Gram blocks  S_c = X_c X_c^T   (all chunks, parallel)
// NOTE: acc[a][b] summation order is identical for (i,j) and (j,i) =>
// S is BIT-EXACTLY symmetric (seq_kernel relies on this for row reads).
// ---------------------------------------------------------------------------
__global__ __launch_bounds__(256) void sgram_kernel(
    const float* __restrict__ xw, float* __restrict__ S_all)
{
  __shared__ __align__(16) float Xs[64 * 396];  // 64 x 392 staged (stride 396)
  const int t = threadIdx.x;
  const int c = blockIdx.x;
  const float* xc = xw + (size_t)c * Cc * Dn;
  const int ti = t >> 4, tj = t & 15;
  float acc[4][4];
#pragma unroll
  for (int a = 0; a < 4; ++a)
#pragma unroll
    for (int b = 0; b < 4; ++b) acc[a][b] = 0.f;

  for (int pass = 0; pass < 2; ++pass) {
    __syncthreads();
    for (int e4 = t; e4 < 64 * 98; e4 += 256) {
      const int r = e4 / 98, c4 = e4 - r * 98;
      *(float4*)&Xs[r * 396 + 4 * c4] =
          *(const float4*)&xc[r * Dn + pass * 392 + 4 * c4];
    }
    __syncthreads();
    for (int k4 = 0; k4 < 98; ++k4) {
      float4 A[4], Bv[4];
#pragma unroll
      for (int a = 0; a < 4; ++a) A[a] = *(const float4*)&Xs[(4 * ti + a) * 396 + 4 * k4];
#pragma unroll
      for (int b = 0; b < 4; ++b) Bv[b] = *(const float4*)&Xs[(4 * tj + b) * 396 + 4 * k4];
#pragma unroll
      for (int a = 0; a < 4; ++a)
#pragma unroll
        for (int b = 0; b < 4; ++b)
          acc[a][b] += A[a].x * Bv[b].x + A[a].y * Bv[b].y + A[a].z * Bv[b].z + A[a].w * Bv[b].w;
    }
  }
  float* Sc = S_all + (size_t)c * Cc * Cc;
#pragma unroll
  for (int a = 0; a < 4; ++a)
#pragma unroll
    for (int b = 0; b < 4; ++b)
      Sc[(4 * ti + a) * Cc + 4 * tj + b] = acc[a][b];
}

// ---------------------------------------------------------------------------
// Kernel 3 (per chunk): yhat[r][h] = sum_d X_c[r][d] * W[h][d]   [64 x 256]
// ---------------------------------------------------------------------------
__global__ __launch_bounds__(256) void yhat_kernel(
    const float* __restrict__ xc, const float* __restrict__ W,
    float* __restrict__ yhat)
{
  const int t = threadIdx.x;
  const int r = t & 63, hh = t >> 6;
  const int h = blockIdx.x * 4 + hh;
  const float4* xr = (const float4*)&xc[r * Dn];
  const float4* wr = (const float4*)&W[h * Dn];
  float acc = 0.f;
#pragma unroll 4
  for (int f = 0; f < 196; ++f) {
    const float4 a = xr[f], b = wr[f];
    acc += a.x * b.x + a.y * b.y + a.z * b.z + a.w * b.w;
  }
  yhat[r * Hn + h] = acc;
}

// ---------------------------------------------------------------------------
// Kernel 3b (per chunk): Ts_g = yhat yhat^T  (moved OUT of seq_kernel).
// Identical summation order to the old in-seq gram => bit-identical values;
// bit-exactly symmetric (same acc order for (i,j)/(j,i)).
// ---------------------------------------------------------------------------
__global__ __launch_bounds__(256, 1) void tgram_kernel(
    const float* __restrict__ yhat_g, float* __restrict__ Ts_g)
{
  __shared__ __align__(16) float Ys[64 * YS];
  const int t = threadIdx.x;
  for (int e4 = t; e4 < 4096; e4 += 256) {
    const int r = e4 >> 6, c4 = e4 & 63;
    *(float4*)&Ys[r * YS + 4 * c4] = ((const float4*)yhat_g)[e4];
  }
  __syncthreads();
  const int ti = t >> 4, tj = t & 15;
  float acc[4][4];
#pragma unroll
  for (int a = 0; a < 4; ++a)
#pragma unroll
    for (int b = 0; b < 4; ++b) acc[a][b] = 0.f;
  for (int k4 = 0; k4 < 64; ++k4) {
    float4 A[4], Bv[4];
#pragma unroll
    for (int a = 0; a < 4; ++a) A[a] = *(const float4*)&Ys[(4 * ti + a) * YS + 4 * k4];
#pragma unroll
    for (int b = 0; b < 4; ++b) Bv[b] = *(const float4*)&Ys[(4 * tj + b) * YS + 4 * k4];
#pragma unroll
    for (int a = 0; a < 4; ++a)
#pragma unroll
      for (int b = 0; b < 4; ++b)
        acc[a][b] += A[a].x * Bv[b].x + A[a].y * Bv[b].y + A[a].z * Bv[b].z + A[a].w * Bv[b].w;
  }
#pragma unroll
  for (int a = 0; a < 4; ++a)
    *(float4*)&Ts_g[(4 * ti + a) * 64 + 4 * tj] =
        make_float4(acc[a][0], acc[a][1], acc[a][2], acc[a][3]);
}

// ---------------------------------------------------------------------------
// Kernel 4 (per chunk): 64-step recurrence, BLOCKED by R=4. Step loop and
// beta export BIT-IDENTICAL to the round-12-passing version. Changes:
//  - Ts loaded from global (tgram_kernel output) instead of in-seq gram
//  - feats epilogue + yh staging removed (feats_kernel does it, parallel)
//  - Al exported to global for feats_kernel
// ---------------------------------------------------------------------------
__global__ __launch_bounds__(256, 1) void seq_kernel(
    const float* __restrict__ Ts_g, const float* __restrict__ S_g,
    float* __restrict__ Al_g, float* __restrict__ beta_g)
{
  __shared__ __align__(16) float lds[8 * MSZ + 1872];  // 146,752 B
  float* Gy  = lds + 0 * MSZ;
  float* AlT = lds + 1 * MSZ;
  float* BeT = lds + 2 * MSZ;
  float* GuT = lds + 3 * MSZ;
  float* Qs  = lds + 4 * MSZ;
  float* Ts  = lds + 5 * MSZ;
  float* Ss  = lds + 6 * MSZ;
  float* Al  = lds + 7 * MSZ;
  float* VOb = lds + 8 * MSZ;        // [4][AS] (row-major by s, for ph1b dots)
  float* VMb = VOb + 4 * AS;         // [4][AS], zeroed at block positions
  float* GVo = VMb + 4 * AS;         // [16]:  GVo[s'*4 + s]
  float* Pk  = GVo + 16;             // [64][20]: og[4]|oq[4]|oa[4]|vo[4]|pad

  const int t = threadIdx.x;
  const int k = t >> 2, qr = t & 3;

  // ---- prologue: zero Gy,AlT,BeT,GuT,Qs (contiguous 5*MSZ) ----
  for (int e4 = t; e4 < 5 * MSZ / 4; e4 += 256)
    *(float4*)&lds[4 * e4] = make_float4(0.f, 0.f, 0.f, 0.f);
  // Ss, Ts <- global (rows stride AS)
  for (int e4 = t; e4 < 1024; e4 += 256) {
    const int r = e4 >> 4, c4 = e4 & 15;
    *(float4*)&Ss[r * AS + 4 * c4] = ((const float4*)S_g)[e4];
    *(float4*)&Ts[r * AS + 4 * c4] = ((const float4*)Ts_g)[e4];
  }
  __syncthreads();

  __builtin_amdgcn_s_setprio(1);

  for (int b = 0; b < Cc / 4; ++b) {
    const int b0 = 4 * b;
    const int wseg = (b0 + 15) >> 4;   // 0..4, wave-uniform
    const int o4 = qr * wseg;          // lane's first float4 index in a row

    // ================= ph1a: outer dots (triangular width) =================
    float4 gyS[4], atS[4], qS[4];
    {
      const float4* gyp = (const float4*)&Gy[k * AS] + o4;
      const float4* atp = (const float4*)&AlT[k * AS] + o4;
      const float4* qp  = (const float4*)&Qs[k * AS] + o4;
#pragma unroll
      for (int f = 0; f < 4; ++f)
        if (f < wseg) { gyS[f] = gyp[f]; atS[f] = atp[f]; qS[f] = qp[f]; }
    }
    float og[4], oq[4], oa[4], grow[4];
#pragma unroll
    for (int s = 0; s < 4; ++s) {
      const float4* pR = (const float4*)&GuT[(b0 + s) * AS] + o4;
      float g0 = 0.f, g1 = 0.f, g2 = 0.f, g3 = 0.f;
      float a0 = 0.f, a1 = 0.f, a2 = 0.f, a3 = 0.f;
      float w0 = 0.f, w1 = 0.f, w2 = 0.f, w3 = 0.f;
#pragma unroll
      for (int f = 0; f < 4; ++f)
        if (f < wseg) {
          const float4 p = pR[f];
          g0 += p.x * gyS[f].x; g1 += p.y * gyS[f].y; g2 += p.z * gyS[f].z; g3 += p.w * gyS[f].w;
          a0 += p.x * atS[f].x; a1 += p.y * atS[f].y; a2 += p.z * atS[f].z; a3 += p.w * atS[f].w;
          w0 += p.x * qS[f].x;  w1 += p.y * qS[f].y;  w2 += p.z * qS[f].z;  w3 += p.w * qS[f].w;
        }
      og[s] = red4((g0 + g1) + (g2 + g3));
      oa[s] = red4((a0 + a1) + (a2 + a3));
      oq[s] = red4((w0 + w1) + (w2 + w3));
      grow[s] = Gy[(b0 + s) * AS + k];
    }
    if (qr == 0)      *(float4*)&Pk[k * 20 + 0] = make_float4(og[0], og[1], og[2], og[3]);
    else if (qr == 1) *(float4*)&Pk[k * 20 + 4] = make_float4(oq[0], oq[1], oq[2], oq[3]);
    else if (qr == 2) *(float4*)&Pk[k * 20 + 8] = make_float4(oa[0], oa[1], oa[2], oa[3]);
    else {
      float vo[4];
#pragma unroll
      for (int s = 0; s < 4; ++s) vo[s] = grow[s] + LRATE * oq[s];
      *(float4*)&Pk[k * 20 + 12] = make_float4(vo[0], vo[1], vo[2], vo[3]);
#pragma unroll
      for (int s = 0; s < 4; ++s) VOb[s * AS + k] = vo[s];
    }
    __syncthreads();

    // ================= ph1b: GVo pair dots (bounded by Gu's zero cols) =====
    if (t < 64) {
      const int pr = t >> 2;          // 0..15: s' = pr>>2, s = pr&3
      const int sp = pr >> 2, s2 = pr & 3;
      const int q2 = t & 3;
      const float4* gr = (const float4*)&GuT[(b0 + sp) * AS] + q2 * wseg;
      const float4* vr = (const float4*)&VOb[s2 * AS] + q2 * wseg;
      float d0 = 0.f, d1 = 0.f, d2 = 0.f, d3 = 0.f;
#pragma unroll
      for (int f = 0; f < 4; ++f)
        if (f < wseg) {
          const float4 g = gr[f], v = vr[f];
          d0 += g.x * v.x; d1 += g.y * v.y; d2 += g.z * v.z; d3 += g.w * v.w;
        }
      const float d = red4((d0 + d1) + (d2 + d3));
      if (q2 == 0) GVo[pr] = d;
    }
    __syncthreads();

    // ================= ph2: redundant 4x4 inner solve =================
    float T8[4][4], S8v[4][4], OG8[4][4], OQ8[4][4], GV8[4][4];
#pragma unroll
    for (int j = 0; j < 4; ++j) {
      const float4 t4 = *(const float4*)&Ts[(b0 + j) * AS + b0];  // T row (sym)
      T8[j][0] = t4.x; T8[j][1] = t4.y; T8[j][2] = t4.z; T8[j][3] = t4.w;
      const float4 s4 = *(const float4*)&Ss[(b0 + j) * AS + b0];  // S row (sym)
      S8v[j][0] = s4.x; S8v[j][1] = s4.y; S8v[j][2] = s4.z; S8v[j][3] = s4.w;
      const float4 g4 = *(const float4*)&Pk[(b0 + j) * 20 + 0];   // og col j
      OG8[0][j] = g4.x; OG8[1][j] = g4.y; OG8[2][j] = g4.z; OG8[3][j] = g4.w;
      const float4 q4 = *(const float4*)&Pk[(b0 + j) * 20 + 4];   // oq col j
      OQ8[0][j] = q4.x; OQ8[1][j] = q4.y; OQ8[2][j] = q4.z; OQ8[3][j] = q4.w;
      const float4 v4 = ((const float4*)GVo)[j];
      GV8[j][0] = v4.x; GV8[j][1] = v4.y; GV8[j][2] = v4.z; GV8[j][3] = v4.w;
    }
    float G8[4][4], V8[4][4], U8[4][4], W8[4][4], Qd[4];
    // s = 0
#pragma unroll
    for (int j = 0; j < 4; ++j) {
      G8[0][j] = T8[0][j] + LRATE * OG8[0][j];
      V8[0][j] = 0.f;
      W8[j][0] = GV8[j][0];
    }
#pragma unroll
    for (int j = 0; j < 4; ++j) U8[0][j] = S8v[0][j] - G8[0][j] - LRATE * W8[j][0];
    Qd[0] = G8[0][0] + LRATE * W8[0][0];
    // s = 1
    {
      const float p0 = U8[0][1];
#pragma unroll
      for (int j = 0; j < 4; ++j) G8[1][j] = T8[1][j] + LRATE * (OG8[1][j] + p0 * G8[0][j]);
      V8[1][0] = G8[0][1] + LRATE * (OQ8[1][0] + p0 * Qd[0]);
      V8[1][1] = V8[1][2] = V8[1][3] = 0.f;
#pragma unroll
      for (int j = 0; j < 4; ++j) W8[j][1] = GV8[j][1] + LRATE * (p0 * W8[j][0]);
#pragma unroll
      for (int j = 0; j < 4; ++j)
        U8[1][j] = S8v[1][j] - G8[1][j] - LRATE * (W8[j][1] + V8[1][0] * U8[0][j]);
      Qd[1] = G8[1][1] + LRATE * (W8[1][1] + p0 * V8[1][0]);
    }
    // s = 2
    {
      const float p0 = U8[0][2], p1 = U8[1][2];
#pragma unroll
      for (int j = 0; j < 4; ++j)
        G8[2][j] = T8[2][j] + LRATE * (OG8[2][j] + p0 * G8[0][j] + p1 * G8[1][j]);
      V8[2][0] = G8[0][2] + LRATE * (OQ8[2][0] + p0 * Qd[0] + p1 * V8[1][0]);
      V8[2][1] = G8[1][2] + LRATE * (OQ8[2][1] + p1 * Qd[1]);  // p0*V8[0][1] = 0
      V8[2][2] = V8[2][3] = 0.f;
#pragma unroll
      for (int j = 0; j < 4; ++j) W8[j][2] = GV8[j][2] + LRATE * (p0 * W8[j][0] + p1 * W8[j][1]);
#pragma unroll
      for (int j = 0; j < 4; ++j)
        U8[2][j] = S8v[2][j] - G8[2][j] -
                   LRATE * (W8[j][2] + V8[2][0] * U8[0][j] + V8[2][1] * U8[1][j]);
      Qd[2] = G8[2][2] + LRATE * (W8[2][2] + p0 * V8[2][0] + p1 * V8[2][1]);
    }
    // s = 3
    {
      const float p0 = U8[0][3], p1 = U8[1][3], p2 = U8[2][3];
#pragma unroll
      for (int j = 0; j < 4; ++j)
        G8[3][j] = T8[3][j] + LRATE * (OG8[3][j] + p0 * G8[0][j] + p1 * G8[1][j] + p2 * G8[2][j]);
      V8[3][0] = G8[0][3] + LRATE * (OQ8[3][0] + p0 * Qd[0] + p1 * V8[1][0] + p2 * V8[2][0]);
      V8[3][1] = G8[1][3] + LRATE * (OQ8[3][1] + p1 * Qd[1] + p2 * V8[2][1]);
      V8[3][2] = G8[2][3] + LRATE * (OQ8[3][2] + p2 * Qd[2]);
      V8[3][3] = 0.f;
#pragma unroll
      for (int j = 0; j < 4; ++j)
        W8[j][3] = GV8[j][3] + LRATE * (p0 * W8[j][0] + p1 * W8[j][1] + p2 * W8[j][2]);
#pragma unroll
      for (int j = 0; j < 4; ++j)
        U8[3][j] = S8v[3][j] - G8[3][j] -
                   LRATE * (W8[j][3] + V8[3][0] * U8[0][j] + V8[3][1] * U8[1][j] +
                            V8[3][2] * U8[2][j]);
      Qd[3] = G8[3][3] + LRATE * (W8[3][3] + p0 * V8[3][0] + p1 * V8[3][1] + p2 * V8[3][2]);
    }

    // ================= ph3: per-thread triangular expansion =================
    float TsK[4], OGk[4], OAk[4], VOk[4];
    {
      const float4 tk4 = *(const float4*)&Ts[k * AS + b0];    // Ts sym row read
      TsK[0] = tk4.x; TsK[1] = tk4.y; TsK[2] = tk4.z; TsK[3] = tk4.w;
      const float4 og4 = *(const float4*)&Pk[k * 20 + 0];
      OGk[0] = og4.x; OGk[1] = og4.y; OGk[2] = og4.z; OGk[3] = og4.w;
      const float4 oa4 = *(const float4*)&Pk[k * 20 + 8];
      OAk[0] = oa4.x; OAk[1] = oa4.y; OAk[2] = oa4.z; OAk[3] = oa4.w;
      const float4 vo4 = *(const float4*)&Pk[k * 20 + 12];
      VOk[0] = vo4.x; VOk[1] = vo4.y; VOk[2] = vo4.z; VOk[3] = vo4.w;
    }
    float gy[4], aI[4], vm[4];
    // s=0
    gy[0] = TsK[0] + LRATE * OGk[0];
    { const float a = LRATE * OAk[0]; aI[0] = (k < b0) ? a : ((k == b0) ? 1.f : 0.f); }
    vm[0] = (k < b0) ? VOk[0] : 0.f;
    // s=1
    {
      const float p0 = U8[0][1];
      gy[1] = TsK[1] + LRATE * (OGk[1] + p0 * gy[0]);
      const float a = LRATE * (OAk[1] + p0 * aI[0]);
      aI[1] = (k < b0 + 1) ? a : ((k == b0 + 1) ? 1.f : 0.f);
      const float vt0 = (k == b0) ? Qd[0] : vm[0];
      float v = VOk[1] + LRATE * (p0 * vt0);
      if (k == b0) v += G8[0][1];
      vm[1] = (k < b0 + 1) ? v : 0.f;
    }
    // s=2
    {
      const float p0 = U8[0][2], p1 = U8[1][2];
      gy[2] = TsK[2] + LRATE * (OGk[2] + p0 * gy[0] + p1 * gy[1]);
      const float a = LRATE * (OAk[2] + p0 * aI[0] + p1 * aI[1]);
      aI[2] = (k < b0 + 2) ? a : ((k == b0 + 2) ? 1.f : 0.f);
      const float vt0 = (k == b0) ? Qd[0] : vm[0];
      const float vt1 = (k == b0 + 1) ? Qd[1] : vm[1];
      float v = VOk[2] + LRATE * (p0 * vt0 + p1 * vt1);
      if (k == b0) v += G8[0][2];
      else if (k == b0 + 1) v += G8[1][2];
      vm[2] = (k < b0 + 2) ? v : 0.f;
    }
    // s=3
    {
      const float p0 = U8[0][3], p1 = U8[1][3], p2 = U8[2][3];
      gy[3] = TsK[3] + LRATE * (OGk[3] + p0 * gy[0] + p1 * gy[1] + p2 * gy[2]);
      const float a = LRATE * (OAk[3] + p0 * aI[0] + p1 * aI[1] + p2 * aI[2]);
      aI[3] = (k < b0 + 3) ? a : ((k == b0 + 3) ? 1.f : 0.f);
      const float vt0 = (k == b0) ? Qd[0] : vm[0];
      const float vt1 = (k == b0 + 1) ? Qd[1] : vm[1];
      const float vt2 = (k == b0 + 2) ? Qd[2] : vm[2];
      float v = VOk[3] + LRATE * (p0 * vt0 + p1 * vt1 + p2 * vt2);
      if (k == b0) v += G8[0][3];
      else if (k == b0 + 1) v += G8[1][3];
      else if (k == b0 + 2) v += G8[2][3];
      vm[3] = (k < b0 + 3) ? v : 0.f;
    }
    // Q writes carry Qd at the diagonal from every writer (race-safe: all
    // writers store the same value). qw[s] = (k==b0+s) ? Qd[s] : vm[s].
    float qw[4];
#pragma unroll
    for (int s = 0; s < 4; ++s) qw[s] = (k == b0 + s) ? Qd[s] : vm[s];
    if (qr == 0) {
      *(float4*)&Gy[k * AS + b0] = make_float4(gy[0], gy[1], gy[2], gy[3]);
#pragma unroll
      for (int s = 0; s < 4; ++s) Qs[(b0 + s) * AS + k] = qw[s];
    } else if (qr == 1) {
      *(float4*)&AlT[k * AS + b0] = make_float4(aI[0], aI[1], aI[2], aI[3]);
      *(float4*)&Qs[k * AS + b0] = make_float4(qw[0], qw[1], qw[2], qw[3]);
    } else if (qr == 2) {
#pragma unroll
      for (int s = 0; s < 4; ++s) Al[(b0 + s) * AS + k] = aI[s];
#pragma unroll
      for (int s = 0; s < 4; ++s) VMb[s * AS + k] = (k < b0) ? vm[s] : 0.f;
    }
    __syncthreads();

    // ================= ph4: b / gu (triangular width) =================
    float4 beS[4], guS[4];
    {
      const float4* bep = (const float4*)&BeT[k * AS] + o4;
      const float4* gup = (const float4*)&GuT[k * AS] + o4;
#pragma unroll
      for (int f = 0; f < 4; ++f)
        if (f < wseg) { beS[f] = bep[f]; guS[f] = gup[f]; }
    }
    float bO[4], gO[4];
#pragma unroll
    for (int s = 0; s < 4; ++s) {
      const float4* vmr = (const float4*)&VMb[s * AS] + o4;
      float b0a = 0.f, b1a = 0.f, b2a = 0.f, b3a = 0.f;
      float u0 = 0.f, u1 = 0.f, u2 = 0.f, u3 = 0.f;
#pragma unroll
      for (int f = 0; f < 4; ++f)
        if (f < wseg) {
          const float4 v = vmr[f];
          b0a += v.x * beS[f].x; b1a += v.y * beS[f].y; b2a += v.z * beS[f].z; b3a += v.w * beS[f].w;
          u0 += v.x * guS[f].x; u1 += v.y * guS[f].y; u2 += v.z * guS[f].z; u3 += v.w * guS[f].w;
        }
      bO[s] = red4((b0a + b1a) + (b2a + b3a));
      gO[s] = red4((u0 + u1) + (u2 + u3));
    }
    float SsK[4];
    {
      const float4 sk4 = *(const float4*)&Ss[k * AS + b0];    // Ss sym row read
      SsK[0] = sk4.x; SsK[1] = sk4.y; SsK[2] = sk4.z; SsK[3] = sk4.w;
    }
    float bI[4], gu[4];
    {
      const float bb = -LRATE * bO[0];
      bI[0] = (k < b0) ? bb : ((k == b0) ? 1.f : 0.f);
      gu[0] = SsK[0] - gy[0] - LRATE * gO[0];
    }
    {
      const float bb = -LRATE * (bO[1] + V8[1][0] * bI[0]);
      bI[1] = (k < b0 + 1) ? bb : ((k == b0 + 1) ? 1.f : 0.f);
      gu[1] = SsK[1] - gy[1] - LRATE * (gO[1] + V8[1][0] * gu[0]);
    }
    {
      const float bb = -LRATE * (bO[2] + V8[2][0] * bI[0] + V8[2][1] * bI[1]);
      bI[2] = (k < b0 + 2) ? bb : ((k == b0 + 2) ? 1.f : 0.f);
      gu[2] = SsK[2] - gy[2] - LRATE * (gO[2] + V8[2][0] * gu[0] + V8[2][1] * gu[1]);
    }
    {
      const float bb = -LRATE * (bO[3] + V8[3][0] * bI[0] + V8[3][1] * bI[1] + V8[3][2] * bI[2]);
      bI[3] = (k < b0 + 3) ? bb : ((k == b0 + 3) ? 1.f : 0.f);
      gu[3] = SsK[3] - gy[3] -
              LRATE * (gO[3] + V8[3][0] * gu[0] + V8[3][1] * gu[1] + V8[3][2] * gu[2]);
    }
    if (qr == 0) {
      *(float4*)&GuT[k * AS + b0] = make_float4(gu[0], gu[1], gu[2], gu[3]);
    } else if (qr == 1) {
      *(float4*)&BeT[k * AS + b0] = make_float4(bI[0], bI[1], bI[2], bI[3]);
    }
    __syncthreads();
  }

  __builtin_amdgcn_s_setprio(0);

  // ---- epilogue: beta export (transpose from BeT) + Al export ----
  {
    const int r = t >> 2, q = t & 3;
#pragma unroll
    for (int kk = 0; kk < 16; ++kk) {
      const int kcol = q * 16 + kk;
      beta_g[r * 64 + kcol] = BeT[kcol * AS + r];
    }
  }
  for (int e4 = t; e4 < 1024; e4 += 256) {
    const int r = e4 >> 4, c4 = e4 & 15;
    ((float4*)Al_g)[e4] = *(const float4*)&Al[r * AS + 4 * c4];
  }
}

// ---------------------------------------------------------------------------
// Kernel 4b (per chunk): feats = Al * yhat  (moved OUT of seq_kernel).
// 4 WGs x 64 threads; per-element arithmetic identical to the old epilogue-3
// (same values, same add order) => bit-identical feats.
// ---------------------------------------------------------------------------
__global__ __launch_bounds__(64) void feats_kernel(
    const float* __restrict__ Al_g, const float* __restrict__ yhat_g,
    float* __restrict__ feats_c)
{
  const int r = threadIdx.x;          // 0..63
  const int m0q4 = blockIdx.x * 64;   // h-quarter base
  float a[64];
#pragma unroll
  for (int f = 0; f < 16; ++f) {
    const float4 av = *(const float4*)&Al_g[r * 64 + 4 * f];
    a[4 * f + 0] = av.x; a[4 * f + 1] = av.y;
    a[4 * f + 2] = av.z; a[4 * f + 3] = av.w;
  }
  float4 acc[16];
#pragma unroll
  for (int f = 0; f < 16; ++f) acc[f] = make_float4(0.f, 0.f, 0.f, 0.f);
#pragma unroll
  for (int m4 = 0; m4 < 16; ++m4) {
    const float av0 = a[4 * m4 + 0], av1 = a[4 * m4 + 1];
    const float av2 = a[4 * m4 + 2], av3 = a[4 * m4 + 3];
    const float4* y0 = (const float4*)&yhat_g[(4 * m4 + 0) * Hn + m0q4];
    const float4* y1 = (const float4*)&yhat_g[(4 * m4 + 1) * Hn + m0q4];
    const float4* y2 = (const float4*)&yhat_g[(4 * m4 + 2) * Hn + m0q4];
    const float4* y3 = (const float4*)&yhat_g[(4 * m4 + 3) * Hn + m0q4];
#pragma unroll
    for (int f = 0; f < 16; ++f) {
      const float4 z0 = y0[f], z1 = y1[f], z2 = y2[f], z3 = y3[f];
      acc[f].x += av0 * z0.x + av1 * z1.x + av2 * z2.x + av3 * z3.x;
      acc[f].y += av0 * z0.y + av1 * z1.y + av2 * z2.y + av3 * z3.y;
      acc[f].z += av0 * z0.z + av1 * z1.z + av2 * z2.z + av3 * z3.z;
      acc[f].w += av0 * z0.w + av1 * z1.w + av2 * z2.w + av3 * z3.w;
    }
  }
  float4* dst = (float4*)&feats_c[r * Hn + m0q4];
#pragma unroll
  for (int f = 0; f < 16; ++f) dst[f] = acc[f];
}

// ---------------------------------------------------------------------------
// Kernel 5 (per chunk): V = X_c - Y W ; U = beta V ; W += LR * Y^T U.
// grid 98 WGs, each owns 8 consecutive W columns.
// ---------------------------------------------------------------------------
__global__ __launch_bounds__(256, 1) void upd_kernel(
    const float* __restrict__ xc, const float* __restrict__ Yg,
    const float* __restrict__ beta_g, float* __restrict__ W)
{
  __shared__ __align__(16) float Yl[64 * YS];
  __shared__ __align__(16) float bl[64 * AS];
  __shared__ __align__(16) float WlT[8 * YS];
  __shared__ __align__(16) float XT[8 * 64];
  __shared__ __align__(16) float VT[8 * 64];
  __shared__ __align__(16) float UT[8 * 64];
  const int t = threadIdx.x;
  const int d0 = blockIdx.x * 8;

  {  // load Y
    const int r = t >> 2, qr = t & 3;
    const float4* src = (const float4*)&Yg[r * Hn + qr * 64];
    float4* dst = (float4*)&Yl[r * YS + qr * 64];
#pragma unroll
    for (int f = 0; f < 16; ++f) dst[f] = src[f];
  }
#pragma unroll
  for (int f = 0; f < 4; ++f) {  // load beta
    const int e4 = t + 256 * f;
    const int r = e4 >> 4, c4 = e4 & 15;
    *(float4*)&bl[r * AS + 4 * c4] = ((const float4*)beta_g)[e4];
  }
  {  // load W slice (transposed)
    const float4* wsrc = (const float4*)&W[t * Dn + d0];
    const float4 w0 = wsrc[0], w1 = wsrc[1];
    WlT[0 * YS + t] = w0.x; WlT[1 * YS + t] = w0.y; WlT[2 * YS + t] = w0.z; WlT[3 * YS + t] = w0.w;
    WlT[4 * YS + t] = w1.x; WlT[5 * YS + t] = w1.y; WlT[6 * YS + t] = w1.z; WlT[7 * YS + t] = w1.w;
  }
  if (t < 64) {  // load X slice (transposed)
    const float4* xsrc = (const float4*)&xc[t * Dn + d0];
    const float4 x0 = xsrc[0], x1 = xsrc[1];
    XT[0 * 64 + t] = x0.x; XT[1 * 64 + t] = x0.y; XT[2 * 64 + t] = x0.z; XT[3 * 64 + t] = x0.w;
    XT[4 * 64 + t] = x1.x; XT[5 * 64 + t] = x1.y; XT[6 * 64 + t] = x1.z; XT[7 * 64 + t] = x1.w;
  }
  __syncthreads();
  const int r = t & 63, da = t >> 6, db = da + 4;
  {  // V = X - Y W
    float va = XT[da * 64 + r], vb = XT[db * 64 + r];
    const float4* yrow = (const float4*)&Yl[r * YS];
    const float4* wa = (const float4*)&WlT[da * YS];
    const float4* wb = (const float4*)&WlT[db * YS];
#pragma unroll 8
    for (int f = 0; f < 64; ++f) {
      const float4 y = yrow[f], A = wa[f], Bv = wb[f];
      va -= y.x * A.x + y.y * A.y + y.z * A.z + y.w * A.w;
      vb -= y.x * Bv.x + y.y * Bv.y + y.z * Bv.z + y.w * Bv.w;
    }
    VT[da * 64 + r] = va; VT[db * 64 + r] = vb;
  }
  __syncthreads();
  {  // U = beta V
    float ua = 0.f, ub = 0.f;
    const float4* br = (const float4*)&bl[r * AS];
    const float4* vta = (const float4*)&VT[da * 64];
    const float4* vtb = (const float4*)&VT[db * 64];
#pragma unroll
    for (int f = 0; f < 16; ++f) {
      const float4 b = br[f], A = vta[f], Bv = vtb[f];
      ua += b.x * A.x + b.y * A.y + b.z * A.z + b.w * A.w;
      ub += b.x * Bv.x + b.y * Bv.y + b.z * Bv.z + b.w * Bv.w;
    }
    UT[da * 64 + r] = ua; UT[db * 64 + r] = ub;
  }
  __syncthreads();
  {  // W[h=t][d0+dj] += LR * sum_r Y[r][h] * U[r][dj]
    float wacc[8];
#pragma unroll
    for (int dj = 0; dj < 8; ++dj) wacc[dj] = 0.f;
    for (int r4 = 0; r4 < 16; ++r4) {
      float4 u[8];
#pragma unroll
      for (int dj = 0; dj < 8; ++dj) u[dj] = *(const float4*)&UT[dj * 64 + 4 * r4];
      const float y0 = Yl[(4 * r4 + 0) * YS + t];
      const float y1 = Yl[(4 * r4 + 1) * YS + t];
      const float y2 = Yl[(4 * r4 + 2) * YS + t];
      const float y3 = Yl[(4 * r4 + 3) * YS + t];
#pragma unroll
      for (int dj = 0; dj < 8; ++dj)
        wacc[dj] += y0 * u[dj].x + y1 * u[dj].y + y2 * u[dj].z + y3 * u[dj].w;
    }
    float4 o0, o1;
    o0.x = WlT[0 * YS + t] + LRATE * wacc[0];
    o0.y = WlT[1 * YS + t] + LRATE * wacc[1];
    o0.z = WlT[2 * YS + t] + LRATE * wacc[2];
    o0.w = WlT[3 * YS + t] + LRATE * wacc[3];
    o1.x = WlT[4 * YS + t] + LRATE * wacc[4];
    o1.y = WlT[5 * YS + t] + LRATE * wacc[5];
    o1.z = WlT[6 * YS + t] + LRATE * wacc[6];
    o1.w = WlT[7 * YS + t] + LRATE * wacc[7];
    float4* wdst = (float4*)&W[t * Dn + d0];
    wdst[0] = o0; wdst[1] = o1;
  }
}

// ---------------------------------------------------------------------------
// Kernel 6: logits = relu(feats) @ R^T + bias
// ---------------------------------------------------------------------------
__global__ __launch_bounds__(256) void readout_kernel(
    const float* __restrict__ feats, const float* __restrict__ R,
    const float* __restrict__ bias, float* __restrict__ out)
{
  const int g = blockIdx.x * 256 + threadIdx.x;
  if (g >= Bn * On) return;
  const int b = g / On;
  const int o = g - b * On;
  const float* f = feats + b * Hn;
  const float* r = R + o * Hn;
  float acc = bias[o];
#pragma unroll 8
  for (int h = 0; h < Hn; ++h) acc += fmaxf(f[h], 0.f) * r[h];
  out[g] = acc;
}

// ---------------------------------------------------------------------------
extern "C" void kernel_launch(void* const* d_in, const int* in_sizes, int n_in,
                              void* d_out, int out_size, void* d_ws, size_t ws_size,
                              hipStream_t stream) {
  const float* x    = (const float*)d_in[0];  // [2048,784]
  const float* mean = (const float*)d_in[1];  // [784]
  const float* Mw   = (const float*)d_in[2];  // [784,784]
  const float* W0   = (const float*)d_in[3];  // [256,784]
  const float* R    = (const float*)d_in[4];  // [10,256]
  const float* bias = (const float*)d_in[5];  // [10]
  float* out = (float*)d_out;                 // [2048,10]

  float* p = (float*)d_ws;
  float* xw     = p;  p += (size_t)Bn * Dn;          // 1,605,632
  float* feats  = p;  p += (size_t)Bn * Hn;          //   524,288
  float* W_dyn  = p;  p += (size_t)Hn * Dn;          //   200,704
  float* S_all  = p;  p += (size_t)NCHUNK * Cc * Cc; //   131,072
  float* yhat   = p;  p += (size_t)Cc * Hn;          //    16,384
  float* beta_g = p;  p += (size_t)Cc * Cc;          //     4,096
  float* Ts_g   = p;  p += (size_t)Cc * Cc;          //     4,096
  float* Al_g   = p;  p += (size_t)Cc * Cc;          //     4,096
  (void)ws_size; (void)n_in; (void)in_sizes; (void)out_size;

  whiten_kernel<<<dim3(Bn / 64, (Dn + 63) / 64), 256, 0, stream>>>(x, mean, Mw, xw);
  sgram_kernel<<<NCHUNK, 256, 0, stream>>>(xw, S_all);
  hipMemcpyAsync(W_dyn, W0, (size_t)Hn * Dn * sizeof(float),
                 hipMemcpyDeviceToDevice, stream);

  for (int c = 0; c < NCHUNK; ++c) {
    const float* xc = xw + (size_t)c * Cc * Dn;
    float* feats_c  = feats + (size_t)c * Cc * Hn;
    yhat_kernel<<<64, 256, 0, stream>>>(xc, W_dyn, yhat);
    tgram_kernel<<<1, 256, 0, stream>>>(yhat, Ts_g);
    seq_kernel<<<1, 256, 0, stream>>>(Ts_g, S_all + (size_t)c * Cc * Cc,
                                      Al_g, beta_g);
    feats_kernel<<<4, 64, 0, stream>>>(Al_g, yhat, feats_c);
    upd_kernel<<<98, 256, 0, stream>>>(xc, feats_c, beta_g, W_dyn);
  }

  readout_kernel<<<(Bn * On + 255) / 256, 256, 0, stream>>>(feats, R, bias, out);
}

// Round 14
// 3972.520 us; speedup vs baseline: 1.2667x; 1.0057x over previous
//
#include <hip/hip_runtime.h>

#define LRATE 1e-3f
static constexpr int Bn = 2048;
static constexpr int Dn = 784;
static constexpr int Hn = 256;
static constexpr int On = 10;
static constexpr int Cc = 64;           // chunk size
static constexpr int NCHUNK = Bn / Cc;  // 32

// LDS row strides (floats): multiples of 4 for aligned float4 (ds_read_b128)
static constexpr int AS = 68;   // 64x64 matrices
static constexpr int YS = 260;  // 64x256 matrices
static constexpr int MSZ = 64 * AS;  // 4352 floats per 64x64 matrix

// 4-lane-group sum via DPP quad_perm (pure VALU; no ds_bpermute)
__device__ __forceinline__ float red4(float s) {
  s += __uint_as_float(__builtin_amdgcn_mov_dpp(__float_as_uint(s), 0xB1, 0xF, 0xF, true)); // xor 1
  s += __uint_as_float(__builtin_amdgcn_mov_dpp(__float_as_uint(s), 0x4E, 0xF, 0xF, true)); // xor 2
  return s;
}

// wave-broadcast read of a lane's register (compile-time lane index)
__device__ __forceinline__ float rl(float v, int lane) {
  return __uint_as_float(__builtin_amdgcn_readlane(__float_as_uint(v), lane));
}

// ---------------------------------------------------------------------------
// Kernel 1: whitening  xw[b,d] = sum_e (x[b,e]-mean[e]) * M[d,e]
// ---------------------------------------------------------------------------
__global__ __launch_bounds__(256) void whiten_kernel(
    const float* __restrict__ x, const float* __restrict__ mean,
    const float* __restrict__ Mw, float* __restrict__ xw)
{
  __shared__ __align__(16) float As[16][64];
  __shared__ __align__(16) float Bs[16][64];
  const int tid = threadIdx.x;
  const int b0 = blockIdx.x * 64;
  const int d0 = blockIdx.y * 64;
  const int mrow = tid >> 2;
  const int kq = (tid & 3) << 2;
  const int ty = tid >> 4, tx = tid & 15;

  float acc[4][4];
#pragma unroll
  for (int i = 0; i < 4; ++i)
#pragma unroll
    for (int j = 0; j < 4; ++j) acc[i][j] = 0.f;

  for (int k0 = 0; k0 < Dn; k0 += 16) {
    __syncthreads();
    {
      const float4 av = *(const float4*)&x[(b0 + mrow) * Dn + k0 + kq];
      const float4 mv = *(const float4*)&mean[k0 + kq];
      As[kq + 0][mrow] = av.x - mv.x;
      As[kq + 1][mrow] = av.y - mv.y;
      As[kq + 2][mrow] = av.z - mv.z;
      As[kq + 3][mrow] = av.w - mv.w;
      float4 bv = make_float4(0.f, 0.f, 0.f, 0.f);
      if (d0 + mrow < Dn) bv = *(const float4*)&Mw[(d0 + mrow) * Dn + k0 + kq];
      Bs[kq + 0][mrow] = bv.x;
      Bs[kq + 1][mrow] = bv.y;
      Bs[kq + 2][mrow] = bv.z;
      Bs[kq + 3][mrow] = bv.w;
    }
    __syncthreads();
#pragma unroll
    for (int k = 0; k < 16; ++k) {
      const float4 a = *(const float4*)&As[k][ty << 2];
      const float4 b = *(const float4*)&Bs[k][tx << 2];
      acc[0][0] += a.x * b.x; acc[0][1] += a.x * b.y; acc[0][2] += a.x * b.z; acc[0][3] += a.x * b.w;
      acc[1][0] += a.y * b.x; acc[1][1] += a.y * b.y; acc[1][2] += a.y * b.z; acc[1][3] += a.y * b.w;
      acc[2][0] += a.z * b.x; acc[2][1] += a.z * b.y; acc[2][2] += a.z * b.z; acc[2][3] += a.z * b.w;
      acc[3][0] += a.w * b.x; acc[3][1] += a.w * b.y; acc[3][2] += a.w * b.z; acc[3][3] += a.w * b.w;
    }
  }
  const int col = d0 + (tx << 2);
  if (col < Dn) {
#pragma unroll
    for (int i = 0; i < 4; ++i) {
      const int row = b0 + (ty << 2) + i;
      *(float4*)&xw[row * Dn + col] =
          make_float4(acc[i][0], acc[i][1], acc[i][2], acc[i][3]);
    }
  }
}

// ---------------------------------------------------------------------------
// Kernel 2: per-chunk Gram blocks  S_c = X_c X_c^T   (all chunks, parallel)
// NOTE: acc[a][b] summation order is identical for (i,j) and (j,i) =>
// S is BIT-EXACTLY symmetric (seq_kernel relies on this for row reads).
// ---------------------------------------------------------------------------
__global__ __launch_bounds__(256) void sgram_kernel(
    const float* __restrict__ xw, float* __restrict__ S_all)
{
  __shared__ __align__(16) float Xs[64 * 396];  // 64 x 392 staged (stride 396)
  const int t = threadIdx.x;
  const int c = blockIdx.x;
  const float* xc = xw + (size_t)c * Cc * Dn;
  const int ti = t >> 4, tj = t & 15;
  float acc[4][4];
#pragma unroll
  for (int a = 0; a < 4; ++a)
#pragma unroll
    for (int b = 0; b < 4; ++b) acc[a][b] = 0.f;

  for (int pass = 0; pass < 2; ++pass) {
    __syncthreads();
    for (int e4 = t; e4 < 64 * 98; e4 += 256) {
      const int r = e4 / 98, c4 = e4 - r * 98;
      *(float4*)&Xs[r * 396 + 4 * c4] =
          *(const float4*)&xc[r * Dn + pass * 392 + 4 * c4];
    }
    __syncthreads();
    for (int k4 = 0; k4 < 98; ++k4) {
      float4 A[4], Bv[4];
#pragma unroll
      for (int a = 0; a < 4; ++a) A[a] = *(const float4*)&Xs[(4 * ti + a) * 396 + 4 * k4];
#pragma unroll
      for (int b = 0; b < 4; ++b) Bv[b] = *(const float4*)&Xs[(4 * tj + b) * 396 + 4 * k4];
#pragma unroll
      for (int a = 0; a < 4; ++a)
#pragma unroll
        for (int b = 0; b < 4; ++b)
          acc[a][b] += A[a].x * Bv[b].x + A[a].y * Bv[b].y + A[a].z * Bv[b].z + A[a].w * Bv[b].w;
    }
  }
  float* Sc = S_all + (size_t)c * Cc * Cc;
#pragma unroll
  for (int a = 0; a < 4; ++a)
#pragma unroll
    for (int b = 0; b < 4; ++b)
      Sc[(4 * ti + a) * Cc + 4 * tj + b] = acc[a][b];
}

// ---------------------------------------------------------------------------
// Kernel 3 (per chunk): yhat[r][h] = sum_d X_c[r][d] * W[h][d]   [64 x 256]
// ---------------------------------------------------------------------------
__global__ __launch_bounds__(256) void yhat_kernel(
    const float* __restrict__ xc, const float* __restrict__ W,
    float* __restrict__ yhat)
{
  const int t = threadIdx.x;
  const int r = t & 63, hh = t >> 6;
  const int h = blockIdx.x * 4 + hh;
  const float4* xr = (const float4*)&xc[r * Dn];
  const float4* wr = (const float4*)&W[h * Dn];
  float acc = 0.f;
#pragma unroll 4
  for (int f = 0; f < 196; ++f) {
    const float4 a = xr[f], b = wr[f];
    acc += a.x * b.x + a.y * b.y + a.z * b.z + a.w * b.w;
  }
  yhat[r * Hn + h] = acc;
}

// ---------------------------------------------------------------------------
// Kernel 3b (per chunk): Ts_g = yhat yhat^T  (bit-symmetric)
// ---------------------------------------------------------------------------
__global__ __launch_bounds__(256, 1) void tgram_kernel(
    const float* __restrict__ yhat_g, float* __restrict__ Ts_g)
{
  __shared__ __align__(16) float Ys[64 * YS];
  const int t = threadIdx.x;
  for (int e4 = t; e4 < 4096; e4 += 256) {
    const int r = e4 >> 6, c4 = e4 & 63;
    *(float4*)&Ys[r * YS + 4 * c4] = ((const float4*)yhat_g)[e4];
  }
  __syncthreads();
  const int ti = t >> 4, tj = t & 15;
  float acc[4][4];
#pragma unroll
  for (int a = 0; a < 4; ++a)
#pragma unroll
    for (int b = 0; b < 4; ++b) acc[a][b] = 0.f;
  for (int k4 = 0; k4 < 64; ++k4) {
    float4 A[4], Bv[4];
#pragma unroll
    for (int a = 0; a < 4; ++a) A[a] = *(const float4*)&Ys[(4 * ti + a) * YS + 4 * k4];
#pragma unroll
    for (int b = 0; b < 4; ++b) Bv[b] = *(const float4*)&Ys[(4 * tj + b) * YS + 4 * k4];
#pragma unroll
    for (int a = 0; a < 4; ++a)
#pragma unroll
      for (int b = 0; b < 4; ++b)
        acc[a][b] += A[a].x * Bv[b].x + A[a].y * Bv[b].y + A[a].z * Bv[b].z + A[a].w * Bv[b].w;
  }
#pragma unroll
  for (int a = 0; a < 4; ++a)
    *(float4*)&Ts_g[(4 * ti + a) * 64 + 4 * tj] =
        make_float4(acc[a][0], acc[a][1], acc[a][2], acc[a][3]);
}

// ---------------------------------------------------------------------------
// Kernel 4 (per chunk): 64-step recurrence, BLOCKED by R=4. Same REAL
// arithmetic as round 13 (bit-identical values); structural changes:
//  - ph1b (GVo pair dots) computed per-wave redundantly and consumed via
//    v_readlane => barrier count 4 -> 3 per block, GVo LDS roundtrip gone
//  - Ts/Ss rows + ph4's old-state BeT/GuT rows prefetched during ph1a
//    (all stable since the previous barrier) => latency overlapped
// ---------------------------------------------------------------------------
__global__ __launch_bounds__(256, 1) void seq_kernel(
    const float* __restrict__ Ts_g, const float* __restrict__ S_g,
    float* __restrict__ Al_g, float* __restrict__ beta_g)
{
  __shared__ __align__(16) float lds[8 * MSZ + 1872];  // 146,752 B
  float* Gy  = lds + 0 * MSZ;
  float* AlT = lds + 1 * MSZ;
  float* BeT = lds + 2 * MSZ;
  float* GuT = lds + 3 * MSZ;
  float* Qs  = lds + 4 * MSZ;
  float* Ts  = lds + 5 * MSZ;
  float* Ss  = lds + 6 * MSZ;
  float* Al  = lds + 7 * MSZ;
  float* VOb = lds + 8 * MSZ;        // [4][AS] (row-major by s, for GVo dots)
  float* VMb = VOb + 4 * AS;         // [4][AS], zeroed at block positions
  float* Pk  = VMb + 4 * AS + 16;    // [64][20]: og[4]|oq[4]|oa[4]|vo[4]|pad

  const int t = threadIdx.x;
  const int k = t >> 2, qr = t & 3;

  // ---- prologue: zero Gy,AlT,BeT,GuT,Qs (contiguous 5*MSZ) ----
  for (int e4 = t; e4 < 5 * MSZ / 4; e4 += 256)
    *(float4*)&lds[4 * e4] = make_float4(0.f, 0.f, 0.f, 0.f);
  // Ss, Ts <- global (rows stride AS)
  for (int e4 = t; e4 < 1024; e4 += 256) {
    const int r = e4 >> 4, c4 = e4 & 15;
    *(float4*)&Ss[r * AS + 4 * c4] = ((const float4*)S_g)[e4];
    *(float4*)&Ts[r * AS + 4 * c4] = ((const float4*)Ts_g)[e4];
  }
  __syncthreads();

  __builtin_amdgcn_s_setprio(1);

  for (int b = 0; b < Cc / 4; ++b) {
    const int b0 = 4 * b;
    const int wseg = (b0 + 15) >> 4;   // 0..4, wave-uniform
    const int o4 = qr * wseg;          // lane's first float4 index in a row

    // ================= ph1a: outer dots (triangular width) =================
    float4 gyS[4], atS[4], qS[4];
    {
      const float4* gyp = (const float4*)&Gy[k * AS] + o4;
      const float4* atp = (const float4*)&AlT[k * AS] + o4;
      const float4* qp  = (const float4*)&Qs[k * AS] + o4;
#pragma unroll
      for (int f = 0; f < 4; ++f)
        if (f < wseg) { gyS[f] = gyp[f]; atS[f] = atp[f]; qS[f] = qp[f]; }
    }
    // prefetch static Ts/Ss rows (never written) and ph4 old-state rows
    // (BeT/GuT rows k, cols < 16*wseg: last written before previous barrier)
    float4 t8row[4], s8row[4], beS[4], guS[4];
#pragma unroll
    for (int j = 0; j < 4; ++j) {
      t8row[j] = *(const float4*)&Ts[(b0 + j) * AS + b0];
      s8row[j] = *(const float4*)&Ss[(b0 + j) * AS + b0];
    }
    const float4 tk4 = *(const float4*)&Ts[k * AS + b0];
    const float4 sk4 = *(const float4*)&Ss[k * AS + b0];
    {
      const float4* bep = (const float4*)&BeT[k * AS] + o4;
      const float4* gup = (const float4*)&GuT[k * AS] + o4;
#pragma unroll
      for (int f = 0; f < 4; ++f)
        if (f < wseg) { beS[f] = bep[f]; guS[f] = gup[f]; }
    }
    float og[4], oq[4], oa[4], grow[4];
#pragma unroll
    for (int s = 0; s < 4; ++s) {
      const float4* pR = (const float4*)&GuT[(b0 + s) * AS] + o4;
      float g0 = 0.f, g1 = 0.f, g2 = 0.f, g3 = 0.f;
      float a0 = 0.f, a1 = 0.f, a2 = 0.f, a3 = 0.f;
      float w0 = 0.f, w1 = 0.f, w2 = 0.f, w3 = 0.f;
#pragma unroll
      for (int f = 0; f < 4; ++f)
        if (f < wseg) {
          const float4 p = pR[f];
          g0 += p.x * gyS[f].x; g1 += p.y * gyS[f].y; g2 += p.z * gyS[f].z; g3 += p.w * gyS[f].w;
          a0 += p.x * atS[f].x; a1 += p.y * atS[f].y; a2 += p.z * atS[f].z; a3 += p.w * atS[f].w;
          w0 += p.x * qS[f].x;  w1 += p.y * qS[f].y;  w2 += p.z * qS[f].z;  w3 += p.w * qS[f].w;
        }
      og[s] = red4((g0 + g1) + (g2 + g3));
      oa[s] = red4((a0 + a1) + (a2 + a3));
      oq[s] = red4((w0 + w1) + (w2 + w3));
      grow[s] = Gy[(b0 + s) * AS + k];
    }
    if (qr == 0)      *(float4*)&Pk[k * 20 + 0] = make_float4(og[0], og[1], og[2], og[3]);
    else if (qr == 1) *(float4*)&Pk[k * 20 + 4] = make_float4(oq[0], oq[1], oq[2], oq[3]);
    else if (qr == 2) *(float4*)&Pk[k * 20 + 8] = make_float4(oa[0], oa[1], oa[2], oa[3]);
    else {
      float vo[4];
#pragma unroll
      for (int s = 0; s < 4; ++s) vo[s] = grow[s] + LRATE * oq[s];
      *(float4*)&Pk[k * 20 + 12] = make_float4(vo[0], vo[1], vo[2], vo[3]);
#pragma unroll
      for (int s = 0; s < 4; ++s) VOb[s * AS + k] = vo[s];
    }
    __syncthreads();  // barrier 1

    // ===== ph1b (per-wave redundant, registers only) + ph2 + ph3 =====
    float gvd;
    {
      const int lane = t & 63;
      const int pr = lane >> 2, q2 = lane & 3;
      const int sp = pr >> 2, s2 = pr & 3;
      const float4* gr = (const float4*)&GuT[(b0 + sp) * AS] + q2 * wseg;
      const float4* vr = (const float4*)&VOb[s2 * AS] + q2 * wseg;
      float d0 = 0.f, d1 = 0.f, d2 = 0.f, d3 = 0.f;
#pragma unroll
      for (int f = 0; f < 4; ++f)
        if (f < wseg) {
          const float4 g = gr[f], v = vr[f];
          d0 += g.x * v.x; d1 += g.y * v.y; d2 += g.z * v.z; d3 += g.w * v.w;
        }
      gvd = red4((d0 + d1) + (d2 + d3));
    }

    // ================= ph2: redundant 4x4 inner solve =================
    float T8[4][4], S8v[4][4], OG8[4][4], OQ8[4][4], GV8[4][4];
#pragma unroll
    for (int j = 0; j < 4; ++j) {
      T8[j][0] = t8row[j].x; T8[j][1] = t8row[j].y; T8[j][2] = t8row[j].z; T8[j][3] = t8row[j].w;
      S8v[j][0] = s8row[j].x; S8v[j][1] = s8row[j].y; S8v[j][2] = s8row[j].z; S8v[j][3] = s8row[j].w;
      const float4 g4 = *(const float4*)&Pk[(b0 + j) * 20 + 0];   // og col j
      OG8[0][j] = g4.x; OG8[1][j] = g4.y; OG8[2][j] = g4.z; OG8[3][j] = g4.w;
      const float4 q4 = *(const float4*)&Pk[(b0 + j) * 20 + 4];   // oq col j
      OQ8[0][j] = q4.x; OQ8[1][j] = q4.y; OQ8[2][j] = q4.z; OQ8[3][j] = q4.w;
      GV8[j][0] = rl(gvd, 4 * (4 * j + 0));
      GV8[j][1] = rl(gvd, 4 * (4 * j + 1));
      GV8[j][2] = rl(gvd, 4 * (4 * j + 2));
      GV8[j][3] = rl(gvd, 4 * (4 * j + 3));
    }
    float G8[4][4], V8[4][4], U8[4][4], W8[4][4], Qd[4];
    // s = 0
#pragma unroll
    for (int j = 0; j < 4; ++j) {
      G8[0][j] = T8[0][j] + LRATE * OG8[0][j];
      V8[0][j] = 0.f;
      W8[j][0] = GV8[j][0];
    }
#pragma unroll
    for (int j = 0; j < 4; ++j) U8[0][j] = S8v[0][j] - G8[0][j] - LRATE * W8[j][0];
    Qd[0] = G8[0][0] + LRATE * W8[0][0];
    // s = 1
    {
      const float p0 = U8[0][1];
#pragma unroll
      for (int j = 0; j < 4; ++j) G8[1][j] = T8[1][j] + LRATE * (OG8[1][j] + p0 * G8[0][j]);
      V8[1][0] = G8[0][1] + LRATE * (OQ8[1][0] + p0 * Qd[0]);
      V8[1][1] = V8[1][2] = V8[1][3] = 0.f;
#pragma unroll
      for (int j = 0; j < 4; ++j) W8[j][1] = GV8[j][1] + LRATE * (p0 * W8[j][0]);
#pragma unroll
      for (int j = 0; j < 4; ++j)
        U8[1][j] = S8v[1][j] - G8[1][j] - LRATE * (W8[j][1] + V8[1][0] * U8[0][j]);
      Qd[1] = G8[1][1] + LRATE * (W8[1][1] + p0 * V8[1][0]);
    }
    // s = 2
    {
      const float p0 = U8[0][2], p1 = U8[1][2];
#pragma unroll
      for (int j = 0; j < 4; ++j)
        G8[2][j] = T8[2][j] + LRATE * (OG8[2][j] + p0 * G8[0][j] + p1 * G8[1][j]);
      V8[2][0] = G8[0][2] + LRATE * (OQ8[2][0] + p0 * Qd[0] + p1 * V8[1][0]);
      V8[2][1] = G8[1][2] + LRATE * (OQ8[2][1] + p1 * Qd[1]);  // p0*V8[0][1] = 0
      V8[2][2] = V8[2][3] = 0.f;
#pragma unroll
      for (int j = 0; j < 4; ++j) W8[j][2] = GV8[j][2] + LRATE * (p0 * W8[j][0] + p1 * W8[j][1]);
#pragma unroll
      for (int j = 0; j < 4; ++j)
        U8[2][j] = S8v[2][j] - G8[2][j] -
                   LRATE * (W8[j][2] + V8[2][0] * U8[0][j] + V8[2][1] * U8[1][j]);
      Qd[2] = G8[2][2] + LRATE * (W8[2][2] + p0 * V8[2][0] + p1 * V8[2][1]);
    }
    // s = 3
    {
      const float p0 = U8[0][3], p1 = U8[1][3], p2 = U8[2][3];
#pragma unroll
      for (int j = 0; j < 4; ++j)
        G8[3][j] = T8[3][j] + LRATE * (OG8[3][j] + p0 * G8[0][j] + p1 * G8[1][j] + p2 * G8[2][j]);
      V8[3][0] = G8[0][3] + LRATE * (OQ8[3][0] + p0 * Qd[0] + p1 * V8[1][0] + p2 * V8[2][0]);
      V8[3][1] = G8[1][3] + LRATE * (OQ8[3][1] + p1 * Qd[1] + p2 * V8[2][1]);
      V8[3][2] = G8[2][3] + LRATE * (OQ8[3][2] + p2 * Qd[2]);
      V8[3][3] = 0.f;
#pragma unroll
      for (int j = 0; j < 4; ++j)
        W8[j][3] = GV8[j][3] + LRATE * (p0 * W8[j][0] + p1 * W8[j][1] + p2 * W8[j][2]);
#pragma unroll
      for (int j = 0; j < 4; ++j)
        U8[3][j] = S8v[3][j] - G8[3][j] -
                   LRATE * (W8[j][3] + V8[3][0] * U8[0][j] + V8[3][1] * U8[1][j] +
                            V8[3][2] * U8[2][j]);
      Qd[3] = G8[3][3] + LRATE * (W8[3][3] + p0 * V8[3][0] + p1 * V8[3][1] + p2 * V8[3][2]);
    }

    // ================= ph3: per-thread triangular expansion =================
    float TsK[4], OGk[4], OAk[4], VOk[4];
    {
      TsK[0] = tk4.x; TsK[1] = tk4.y; TsK[2] = tk4.z; TsK[3] = tk4.w;
      const float4 og4 = *(const float4*)&Pk[k * 20 + 0];
      OGk[0] = og4.x; OGk[1] = og4.y; OGk[2] = og4.z; OGk[3] = og4.w;
      const float4 oa4 = *(const float4*)&Pk[k * 20 + 8];
      OAk[0] = oa4.x; OAk[1] = oa4.y; OAk[2] = oa4.z; OAk[3] = oa4.w;
      const float4 vo4 = *(const float4*)&Pk[k * 20 + 12];
      VOk[0] = vo4.x; VOk[1] = vo4.y; VOk[2] = vo4.z; VOk[3] = vo4.w;
    }
    float gy[4], aI[4], vm[4];
    // s=0
    gy[0] = TsK[0] + LRATE * OGk[0];
    { const float a = LRATE * OAk[0]; aI[0] = (k < b0) ? a : ((k == b0) ? 1.f : 0.f); }
    vm[0] = (k < b0) ? VOk[0] : 0.f;
    // s=1
    {
      const float p0 = U8[0][1];
      gy[1] = TsK[1] + LRATE * (OGk[1] + p0 * gy[0]);
      const float a = LRATE * (OAk[1] + p0 * aI[0]);
      aI[1] = (k < b0 + 1) ? a : ((k == b0 + 1) ? 1.f : 0.f);
      const float vt0 = (k == b0) ? Qd[0] : vm[0];
      float v = VOk[1] + LRATE * (p0 * vt0);
      if (k == b0) v += G8[0][1];
      vm[1] = (k < b0 + 1) ? v : 0.f;
    }
    // s=2
    {
      const float p0 = U8[0][2], p1 = U8[1][2];
      gy[2] = TsK[2] + LRATE * (OGk[2] + p0 * gy[0] + p1 * gy[1]);
      const float a = LRATE * (OAk[2] + p0 * aI[0] + p1 * aI[1]);
      aI[2] = (k < b0 + 2) ? a : ((k == b0 + 2) ? 1.f : 0.f);
      const float vt0 = (k == b0) ? Qd[0] : vm[0];
      const float vt1 = (k == b0 + 1) ? Qd[1] : vm[1];
      float v = VOk[2] + LRATE * (p0 * vt0 + p1 * vt1);
      if (k == b0) v += G8[0][2];
      else if (k == b0 + 1) v += G8[1][2];
      vm[2] = (k < b0 + 2) ? v : 0.f;
    }
    // s=3
    {
      const float p0 = U8[0][3], p1 = U8[1][3], p2 = U8[2][3];
      gy[3] = TsK[3] + LRATE * (OGk[3] + p0 * gy[0] + p1 * gy[1] + p2 * gy[2]);
      const float a = LRATE * (OAk[3] + p0 * aI[0] + p1 * aI[1] + p2 * aI[2]);
      aI[3] = (k < b0 + 3) ? a : ((k == b0 + 3) ? 1.f : 0.f);
      const float vt0 = (k == b0) ? Qd[0] : vm[0];
      const float vt1 = (k == b0 + 1) ? Qd[1] : vm[1];
      const float vt2 = (k == b0 + 2) ? Qd[2] : vm[2];
      float v = VOk[3] + LRATE * (p0 * vt0 + p1 * vt1 + p2 * vt2);
      if (k == b0) v += G8[0][3];
      else if (k == b0 + 1) v += G8[1][3];
      else if (k == b0 + 2) v += G8[2][3];
      vm[3] = (k < b0 + 3) ? v : 0.f;
    }
    // Q writes carry Qd at the diagonal from every writer (race-safe: all
    // writers store the same value). qw[s] = (k==b0+s) ? Qd[s] : vm[s].
    float qw[4];
#pragma unroll
    for (int s = 0; s < 4; ++s) qw[s] = (k == b0 + s) ? Qd[s] : vm[s];
    if (qr == 0) {
      *(float4*)&Gy[k * AS + b0] = make_float4(gy[0], gy[1], gy[2], gy[3]);
#pragma unroll
      for (int s = 0; s < 4; ++s) Qs[(b0 + s) * AS + k] = qw[s];
    } else if (qr == 1) {
      *(float4*)&AlT[k * AS + b0] = make_float4(aI[0], aI[1], aI[2], aI[3]);
      *(float4*)&Qs[k * AS + b0] = make_float4(qw[0], qw[1], qw[2], qw[3]);
    } else if (qr == 2) {
#pragma unroll
      for (int s = 0; s < 4; ++s) Al[(b0 + s) * AS + k] = aI[s];
#pragma unroll
      for (int s = 0; s < 4; ++s) VMb[s * AS + k] = (k < b0) ? vm[s] : 0.f;
    }
    __syncthreads();  // barrier 2

    // ================= ph4: b / gu (triangular width) =================
    float bO[4], gO[4];
#pragma unroll
    for (int s = 0; s < 4; ++s) {
      const float4* vmr = (const float4*)&VMb[s * AS] + o4;
      float b0a = 0.f, b1a = 0.f, b2a = 0.f, b3a = 0.f;
      float u0 = 0.f, u1 = 0.f, u2 = 0.f, u3 = 0.f;
#pragma unroll
      for (int f = 0; f < 4; ++f)
        if (f < wseg) {
          const float4 v = vmr[f];
          b0a += v.x * beS[f].x; b1a += v.y * beS[f].y; b2a += v.z * beS[f].z; b3a += v.w * beS[f].w;
          u0 += v.x * guS[f].x; u1 += v.y * guS[f].y; u2 += v.z * guS[f].z; u3 += v.w * guS[f].w;
        }
      bO[s] = red4((b0a + b1a) + (b2a + b3a));
      gO[s] = red4((u0 + u1) + (u2 + u3));
    }
    float SsK[4];
    { SsK[0] = sk4.x; SsK[1] = sk4.y; SsK[2] = sk4.z; SsK[3] = sk4.w; }
    float bI[4], gu[4];
    {
      const float bb = -LRATE * bO[0];
      bI[0] = (k < b0) ? bb : ((k == b0) ? 1.f : 0.f);
      gu[0] = SsK[0] - gy[0] - LRATE * gO[0];
    }
    {
      const float bb = -LRATE * (bO[1] + V8[1][0] * bI[0]);
      bI[1] = (k < b0 + 1) ? bb : ((k == b0 + 1) ? 1.f : 0.f);
      gu[1] = SsK[1] - gy[1] - LRATE * (gO[1] + V8[1][0] * gu[0]);
    }
    {
      const float bb = -LRATE * (bO[2] + V8[2][0] * bI[0] + V8[2][1] * bI[1]);
      bI[2] = (k < b0 + 2) ? bb : ((k == b0 + 2) ? 1.f : 0.f);
      gu[2] = SsK[2] - gy[2] - LRATE * (gO[2] + V8[2][0] * gu[0] + V8[2][1] * gu[1]);
    }
    {
      const float bb = -LRATE * (bO[3] + V8[3][0] * bI[0] + V8[3][1] * bI[1] + V8[3][2] * bI[2]);
      bI[3] = (k < b0 + 3) ? bb : ((k == b0 + 3) ? 1.f : 0.f);
      gu[3] = SsK[3] - gy[3] -
              LRATE * (gO[3] + V8[3][0] * gu[0] + V8[3][1] * gu[1] + V8[3][2] * gu[2]);
    }
    if (qr == 0) {
      *(float4*)&GuT[k * AS + b0] = make_float4(gu[0], gu[1], gu[2], gu[3]);
    } else if (qr == 1) {
      *(float4*)&BeT[k * AS + b0] = make_float4(bI[0], bI[1], bI[2], bI[3]);
    }
    __syncthreads();  // barrier 3
  }

  __builtin_amdgcn_s_setprio(0);

  // ---- epilogue: beta export (transpose from BeT) + Al export ----
  {
    const int r = t >> 2, q = t & 3;
#pragma unroll
    for (int kk = 0; kk < 16; ++kk) {
      const int kcol = q * 16 + kk;
      beta_g[r * 64 + kcol] = BeT[kcol * AS + r];
    }
  }
  for (int e4 = t; e4 < 1024; e4 += 256) {
    const int r = e4 >> 4, c4 = e4 & 15;
    ((float4*)Al_g)[e4] = *(const float4*)&Al[r * AS + 4 * c4];
  }
}

// ---------------------------------------------------------------------------
// Kernel 4b (per chunk): feats = Al * yhat (bit-identical expression)
// ---------------------------------------------------------------------------
__global__ __launch_bounds__(64) void feats_kernel(
    const float* __restrict__ Al_g, const float* __restrict__ yhat_g,
    float* __restrict__ feats_c)
{
  const int r = threadIdx.x;          // 0..63
  const int m0q4 = blockIdx.x * 64;   // h-quarter base
  float a[64];
#pragma unroll
  for (int f = 0; f < 16; ++f) {
    const float4 av = *(const float4*)&Al_g[r * 64 + 4 * f];
    a[4 * f + 0] = av.x; a[4 * f + 1] = av.y;
    a[4 * f + 2] = av.z; a[4 * f + 3] = av.w;
  }
  float4 acc[16];
#pragma unroll
  for (int f = 0; f < 16; ++f) acc[f] = make_float4(0.f, 0.f, 0.f, 0.f);
#pragma unroll
  for (int m4 = 0; m4 < 16; ++m4) {
    const float av0 = a[4 * m4 + 0], av1 = a[4 * m4 + 1];
    const float av2 = a[4 * m4 + 2], av3 = a[4 * m4 + 3];
    const float4* y0 = (const float4*)&yhat_g[(4 * m4 + 0) * Hn + m0q4];
    const float4* y1 = (const float4*)&yhat_g[(4 * m4 + 1) * Hn + m0q4];
    const float4* y2 = (const float4*)&yhat_g[(4 * m4 + 2) * Hn + m0q4];
    const float4* y3 = (const float4*)&yhat_g[(4 * m4 + 3) * Hn + m0q4];
#pragma unroll
    for (int f = 0; f < 16; ++f) {
      const float4 z0 = y0[f], z1 = y1[f], z2 = y2[f], z3 = y3[f];
      acc[f].x += av0 * z0.x + av1 * z1.x + av2 * z2.x + av3 * z3.x;
      acc[f].y += av0 * z0.y + av1 * z1.y + av2 * z2.y + av3 * z3.y;
      acc[f].z += av0 * z0.z + av1 * z1.z + av2 * z2.z + av3 * z3.z;
      acc[f].w += av0 * z0.w + av1 * z1.w + av2 * z2.w + av3 * z3.w;
    }
  }
  float4* dst = (float4*)&feats_c[r * Hn + m0q4];
#pragma unroll
  for (int f = 0; f < 16; ++f) dst[f] = acc[f];
}

// ---------------------------------------------------------------------------
// Kernel 5 (per chunk): V = X_c - Y W ; U = beta V ; W += LR * Y^T U.
// grid 98 WGs, each owns 8 consecutive W columns.
// ---------------------------------------------------------------------------
__global__ __launch_bounds__(256, 1) void upd_kernel(
    const float* __restrict__ xc, const float* __restrict__ Yg,
    const float* __restrict__ beta_g, float* __restrict__ W)
{
  __shared__ __align__(16) float Yl[64 * YS];
  __shared__ __align__(16) float bl[64 * AS];
  __shared__ __align__(16) float WlT[8 * YS];
  __shared__ __align__(16) float XT[8 * 64];
  __shared__ __align__(16) float VT[8 * 64];
  __shared__ __align__(16) float UT[8 * 64];
  const int t = threadIdx.x;
  const int d0 = blockIdx.x * 8;

  {  // load Y
    const int r = t >> 2, qr = t & 3;
    const float4* src = (const float4*)&Yg[r * Hn + qr * 64];
    float4* dst = (float4*)&Yl[r * YS + qr * 64];
#pragma unroll
    for (int f = 0; f < 16; ++f) dst[f] = src[f];
  }
#pragma unroll
  for (int f = 0; f < 4; ++f) {  // load beta
    const int e4 = t + 256 * f;
    const int r = e4 >> 4, c4 = e4 & 15;
    *(float4*)&bl[r * AS + 4 * c4] = ((const float4*)beta_g)[e4];
  }
  {  // load W slice (transposed)
    const float4* wsrc = (const float4*)&W[t * Dn + d0];
    const float4 w0 = wsrc[0], w1 = wsrc[1];
    WlT[0 * YS + t] = w0.x; WlT[1 * YS + t] = w0.y; WlT[2 * YS + t] = w0.z; WlT[3 * YS + t] = w0.w;
    WlT[4 * YS + t] = w1.x; WlT[5 * YS + t] = w1.y; WlT[6 * YS + t] = w1.z; WlT[7 * YS + t] = w1.w;
  }
  if (t < 64) {  // load X slice (transposed)
    const float4* xsrc = (const float4*)&xc[t * Dn + d0];
    const float4 x0 = xsrc[0], x1 = xsrc[1];
    XT[0 * 64 + t] = x0.x; XT[1 * 64 + t] = x0.y; XT[2 * 64 + t] = x0.z; XT[3 * 64 + t] = x0.w;
    XT[4 * 64 + t] = x1.x; XT[5 * 64 + t] = x1.y; XT[6 * 64 + t] = x1.z; XT[7 * 64 + t] = x1.w;
  }
  __syncthreads();
  const int r = t & 63, da = t >> 6, db = da + 4;
  {  // V = X - Y W
    float va = XT[da * 64 + r], vb = XT[db * 64 + r];
    const float4* yrow = (const float4*)&Yl[r * YS];
    const float4* wa = (const float4*)&WlT[da * YS];
    const float4* wb = (const float4*)&WlT[db * YS];
#pragma unroll 8
    for (int f = 0; f < 64; ++f) {
      const float4 y = yrow[f], A = wa[f], Bv = wb[f];
      va -= y.x * A.x + y.y * A.y + y.z * A.z + y.w * A.w;
      vb -= y.x * Bv.x + y.y * Bv.y + y.z * Bv.z + y.w * Bv.w;
    }
    VT[da * 64 + r] = va; VT[db * 64 + r] = vb;
  }
  __syncthreads();
  {  // U = beta V
    float ua = 0.f, ub = 0.f;
    const float4* br = (const float4*)&bl[r * AS];
    const float4* vta = (const float4*)&VT[da * 64];
    const float4* vtb = (const float4*)&VT[db * 64];
#pragma unroll
    for (int f = 0; f < 16; ++f) {
      const float4 b = br[f], A = vta[f], Bv = vtb[f];
      ua += b.x * A.x + b.y * A.y + b.z * A.z + b.w * A.w;
      ub += b.x * Bv.x + b.y * Bv.y + b.z * Bv.z + b.w * Bv.w;
    }
    UT[da * 64 + r] = ua; UT[db * 64 + r] = ub;
  }
  __syncthreads();
  {  // W[h=t][d0+dj] += LR * sum_r Y[r][h] * U[r][dj]
    float wacc[8];
#pragma unroll
    for (int dj = 0; dj < 8; ++dj) wacc[dj] = 0.f;
    for (int r4 = 0; r4 < 16; ++r4) {
      float4 u[8];
#pragma unroll
      for (int dj = 0; dj < 8; ++dj) u[dj] = *(const float4*)&UT[dj * 64 + 4 * r4];
      const float y0 = Yl[(4 * r4 + 0) * YS + t];
      const float y1 = Yl[(4 * r4 + 1) * YS + t];
      const float y2 = Yl[(4 * r4 + 2) * YS + t];
      const float y3 = Yl[(4 * r4 + 3) * YS + t];
#pragma unroll
      for (int dj = 0; dj < 8; ++dj)
        wacc[dj] += y0 * u[dj].x + y1 * u[dj].y + y2 * u[dj].z + y3 * u[dj].w;
    }
    float4 o0, o1;
    o0.x = WlT[0 * YS + t] + LRATE * wacc[0];
    o0.y = WlT[1 * YS + t] + LRATE * wacc[1];
    o0.z = WlT[2 * YS + t] + LRATE * wacc[2];
    o0.w = WlT[3 * YS + t] + LRATE * wacc[3];
    o1.x = WlT[4 * YS + t] + LRATE * wacc[4];
    o1.y = WlT[5 * YS + t] + LRATE * wacc[5];
    o1.z = WlT[6 * YS + t] + LRATE * wacc[6];
    o1.w = WlT[7 * YS + t] + LRATE * wacc[7];
    float4* wdst = (float4*)&W[t * Dn + d0];
    wdst[0] = o0; wdst[1] = o1;
  }
}

// ---------------------------------------------------------------------------
// Kernel 6: logits = relu(feats) @ R^T + bias
// ---------------------------------------------------------------------------
__global__ __launch_bounds__(256) void readout_kernel(
    const float* __restrict__ feats, const float* __restrict__ R,
    const float* __restrict__ bias, float* __restrict__ out)
{
  const int g = blockIdx.x * 256 + threadIdx.x;
  if (g >= Bn * On) return;
  const int b = g / On;
  const int o = g - b * On;
  const float* f = feats + b * Hn;
  const float* r = R + o * Hn;
  float acc = bias[o];
#pragma unroll 8
  for (int h = 0; h < Hn; ++h) acc += fmaxf(f[h], 0.f) * r[h];
  out[g] = acc;
}

// ---------------------------------------------------------------------------
extern "C" void kernel_launch(void* const* d_in, const int* in_sizes, int n_in,
                              void* d_out, int out_size, void* d_ws, size_t ws_size,
                              hipStream_t stream) {
  const float* x    = (const float*)d_in[0];  // [2048,784]
  const float* mean = (const float*)d_in[1];  // [784]
  const float* Mw   = (const float*)d_in[2];  // [784,784]
  const float* W0   = (const float*)d_in[3];  // [256,784]
  const float* R    = (const float*)d_in[4];  // [10,256]
  const float* bias = (const float*)d_in[5];  // [10]
  float* out = (float*)d_out;                 // [2048,10]

  float* p = (float*)d_ws;
  float* xw     = p;  p += (size_t)Bn * Dn;          // 1,605,632
  float* feats  = p;  p += (size_t)Bn * Hn;          //   524,288
  float* W_dyn  = p;  p += (size_t)Hn * Dn;          //   200,704
  float* S_all  = p;  p += (size_t)NCHUNK * Cc * Cc; //   131,072
  float* yhat   = p;  p += (size_t)Cc * Hn;          //    16,384
  float* beta_g = p;  p += (size_t)Cc * Cc;          //     4,096
  float* Ts_g   = p;  p += (size_t)Cc * Cc;          //     4,096
  float* Al_g   = p;  p += (size_t)Cc * Cc;          //     4,096
  (void)ws_size; (void)n_in; (void)in_sizes; (void)out_size;

  whiten_kernel<<<dim3(Bn / 64, (Dn + 63) / 64), 256, 0, stream>>>(x, mean, Mw, xw);
  sgram_kernel<<<NCHUNK, 256, 0, stream>>>(xw, S_all);
  hipMemcpyAsync(W_dyn, W0, (size_t)Hn * Dn * sizeof(float),
                 hipMemcpyDeviceToDevice, stream);

  for (int c = 0; c < NCHUNK; ++c) {
    const float* xc = xw + (size_t)c * Cc * Dn;
    float* feats_c  = feats + (size_t)c * Cc * Hn;
    yhat_kernel<<<64, 256, 0, stream>>>(xc, W_dyn, yhat);
    tgram_kernel<<<1, 256, 0, stream>>>(yhat, Ts_g);
    seq_kernel<<<1, 256, 0, stream>>>(Ts_g, S_all + (size_t)c * Cc * Cc,
                                      Al_g, beta_g);
    feats_kernel<<<4, 64, 0, stream>>>(Al_g, yhat, feats_c);
    upd_kernel<<<98, 256, 0, stream>>>(xc, feats_c, beta_g, W_dyn);
  }

  readout_kernel<<<(Bn * On + 255) / 256, 256, 0, stream>>>(feats, R, bias, out);
}